// Round 9
// baseline (202.408 us; speedup 1.0000x reference)
//
#include <hip/hip_runtime.h>
#include <math.h>

#define E_DIM 512
#define H_DIM 8
#define WIN 128
#define L_SEQ 4096
#define B_SZ 2

typedef unsigned short ushort_t;
typedef unsigned int uint_t;
typedef __attribute__((ext_vector_type(8))) __bf16 bf16x8;
typedef __attribute__((ext_vector_type(4))) float f32x4;

// ---------- bf16 helpers (manual, RNE) ----------
__device__ __forceinline__ ushort_t f2bf(float f) {
    uint_t u = __float_as_uint(f);
    u = u + 0x7fffu + ((u >> 16) & 1u);
    return (ushort_t)(u >> 16);
}
__device__ __forceinline__ float bf2f(ushort_t h) {
    return __uint_as_float((uint_t)h << 16);
}

__device__ __forceinline__ void gload16(const ushort_t* g, ushort_t* l) {
    __builtin_amdgcn_global_load_lds(
        (const __attribute__((address_space(1))) void*)g,
        (__attribute__((address_space(3))) void*)l,
        16, 0, 0);
}

// ===== Tile image (16 rows x 32 k = 512 elems = 1 KB) =====
// idx = slot*8 + (k&7), slot = ((k>>3)&3)*16 + (row&15)  [slot = quad*16+ln]
// A-frag & B-frag both read at lane*8 within a tile image.

// ---------- split-convert weights only into tiled layout ----------
// slot-groups (8 elems): w1 98304, w2 32768 -> 131072 total
__global__ __launch_bounds__(256) void convertW(
    const float* __restrict__ w1, ushort_t* __restrict__ w1h, ushort_t* __restrict__ w1l,
    const float* __restrict__ w2, ushort_t* __restrict__ w2h, ushort_t* __restrict__ w2l) {
    int sg = blockIdx.x * 256 + threadIdx.x;
    const float* src; ushort_t* dh; ushort_t* dl;
    if (sg < 98304) { src = w1; dh = w1h; dl = w1l; }
    else            { src = w2; dh = w2h; dl = w2l; sg -= 98304; }
    const int tile = sg >> 6, slot = sg & 63;
    const int row = (tile >> 4) * 16 + (slot & 15);
    const int k   = (tile & 15) * 32 + (slot >> 4) * 8;
    const float4 v0 = *(const float4*)&src[(size_t)row * 512 + k];
    const float4 v1 = *(const float4*)&src[(size_t)row * 512 + k + 4];
    const float vv[8] = {v0.x, v0.y, v0.z, v0.w, v1.x, v1.y, v1.z, v1.w};
    union { ushort_t u[8]; ushort4 v[2]; } h, l;
    #pragma unroll
    for (int j = 0; j < 8; j++) {
        const ushort_t a = f2bf(vv[j]);
        h.u[j] = a;
        l.u[j] = f2bf(vv[j] - bf2f(a));
    }
    ((ushort4*)(dh + (size_t)sg * 8))[0] = h.v[0];
    ((ushort4*)(dh + (size_t)sg * 8))[1] = h.v[1];
    ((ushort4*)(dl + (size_t)sg * 8))[0] = l.v[0];
    ((ushort4*)(dl + (size_t)sg * 8))[1] = l.v[1];
}

// ---------- GEMM1: qkv projection ----------
// A staged from row-major f32 x (inline hi/lo split, bit-identical to the old
// convert3 path); W staged via gload16 from pre-tiled split weights.
// 128x128 tile, BK=32, grid (64, 12). by<4: q, [4,8): k, >=8: v.
__global__ __launch_bounds__(256) void gemm_qkv(
    const float* __restrict__ X,
    const ushort_t* __restrict__ Wh, const ushort_t* __restrict__ Wl,
    const float* __restrict__ bias,
    ushort_t* __restrict__ qTh, ushort_t* __restrict__ qTl,
    ushort_t* __restrict__ kTh, ushort_t* __restrict__ kTl,
    ushort_t* __restrict__ vTh) {
    __shared__ __align__(16) ushort_t sAh[8 * 512];
    __shared__ __align__(16) ushort_t sAl[8 * 512];
    __shared__ __align__(16) ushort_t sWh[8 * 512];
    __shared__ __align__(16) ushort_t sWl[8 * 512];

    const int tid = threadIdx.x, lane = tid & 63, w = tid >> 6;
    const int wm = w & 1, wn = w >> 1, ln = lane & 15, quad = lane >> 4;
    const int bx = blockIdx.x, by = blockIdx.y;
    const int lo8 = lane * 8;

    f32x4 acc[4][4];
    const f32x4 zero = {0.f, 0.f, 0.f, 0.f};
    #pragma unroll
    for (int i = 0; i < 4; i++)
        #pragma unroll
        for (int j = 0; j < 4; j++) acc[i][j] = zero;

    // A staging assignment: thread -> (tile, row, k-half)
    const int at   = tid >> 5;          // 0..7
    const int arow = (tid >> 1) & 15;   // 0..15
    const int akh  = tid & 1;           // 0..1 (16-elem half of BK)
    const float* ax = X + (size_t)(bx * 128 + at * 16 + arow) * 512 + akh * 16;
    ushort_t* aldsH0 = &sAh[at * 512 + ((akh * 2 + 0) * 16 + arow) * 8];
    ushort_t* aldsH1 = &sAh[at * 512 + ((akh * 2 + 1) * 16 + arow) * 8];
    ushort_t* aldsL0 = &sAl[at * 512 + ((akh * 2 + 0) * 16 + arow) * 8];
    ushort_t* aldsL1 = &sAl[at * 512 + ((akh * 2 + 1) * 16 + arow) * 8];

    // W staging (wave-uniform roles, as before)
    const ushort_t* wSrc = (w & 2) ? Wl : Wh;
    ushort_t* wDst = (w & 2) ? sWl : sWh;
    const int wt0 = (w & 1) * 4;
    const ushort_t* pw[4];
    #pragma unroll
    for (int t = 0; t < 4; t++)
        pw[t] = wSrc + ((size_t)(by * 8 + wt0 + t) * 16) * 512;

    for (int kt = 0; kt < 16; kt++) {
        const int koff = kt * 512;
        __syncthreads();
        // A: 16 f32 -> split -> LDS
        {
            float4 a4[4];
            #pragma unroll
            for (int q4 = 0; q4 < 4; q4++)
                a4[q4] = ((const float4*)ax)[kt * 8 + q4];
            union { ushort_t u[8]; bf16x8 v; } h0, h1, l0, l1;
            #pragma unroll
            for (int j = 0; j < 8; j++) {
                const float f = ((const float*)a4)[j];
                const ushort_t a = f2bf(f);
                h0.u[j] = a; l0.u[j] = f2bf(f - bf2f(a));
            }
            #pragma unroll
            for (int j = 0; j < 8; j++) {
                const float f = ((const float*)a4)[8 + j];
                const ushort_t a = f2bf(f);
                h1.u[j] = a; l1.u[j] = f2bf(f - bf2f(a));
            }
            *(bf16x8*)aldsH0 = h0.v;
            *(bf16x8*)aldsH1 = h1.v;
            *(bf16x8*)aldsL0 = l0.v;
            *(bf16x8*)aldsL1 = l1.v;
        }
        // W: async direct-to-LDS
        #pragma unroll
        for (int t = 0; t < 4; t++)
            gload16(pw[t] + koff + lo8, &wDst[(wt0 + t) * 512]);
        __syncthreads();

        bf16x8 fah[4], fal[4];
        #pragma unroll
        for (int i = 0; i < 4; i++) {
            fah[i] = *(const bf16x8*)&sAh[(wm * 4 + i) * 512 + lo8];
            fal[i] = *(const bf16x8*)&sAl[(wm * 4 + i) * 512 + lo8];
        }
        #pragma unroll
        for (int j = 0; j < 4; j++) {
            const bf16x8 fbh = *(const bf16x8*)&sWh[(wn * 4 + j) * 512 + lo8];
            const bf16x8 fbl = *(const bf16x8*)&sWl[(wn * 4 + j) * 512 + lo8];
            #pragma unroll
            for (int i = 0; i < 4; i++) {
                acc[i][j] = __builtin_amdgcn_mfma_f32_16x16x32_bf16(fah[i], fbh, acc[i][j], 0, 0, 0);
                acc[i][j] = __builtin_amdgcn_mfma_f32_16x16x32_bf16(fah[i], fbl, acc[i][j], 0, 0, 0);
                acc[i][j] = __builtin_amdgcn_mfma_f32_16x16x32_bf16(fal[i], fbh, acc[i][j], 0, 0, 0);
            }
        }
    }

    // ---- epilogue: C/D layout col=ln (within j-tile), row=quad*4+r ----
    const int b = bx >> 5;               // batch
    const int h = 2 * (by & 3) + wn;     // head (wave-uniform)
    if (by < 8) {
        ushort_t* dh = (by < 4) ? qTh : kTh;
        ushort_t* dl = (by < 4) ? qTl : kTl;
        #pragma unroll
        for (int i = 0; i < 4; i++) {
            const int rt = (bx & 31) * 8 + wm * 4 + i;   // row-tile within batch
            const size_t tb = ((size_t)(b * 8 + h) * 256 + rt) * 2;
            #pragma unroll
            for (int j = 0; j < 4; j++) {
                const float bv = bias[by * 128 + wn * 64 + j * 16 + ln];
                const size_t tile = tb + (j >> 1);
                #pragma unroll
                for (int r = 0; r < 4; r++) {
                    const int slot = ((j * 2 + (ln >> 3)) & 3) * 16 + quad * 4 + r;
                    const size_t idx = tile * 512 + slot * 8 + (ln & 7);
                    const float v = acc[i][j][r] + bv;
                    const ushort_t hh = f2bf(v);
                    dh[idx] = hh;
                    dl[idx] = f2bf(v - bf2f(hh));
                }
            }
        }
    } else {
        // v: hi only, transposed tiles (rows = d, k = kseq)
        const int kwin = (bx & 31) * 2 + wm;
        #pragma unroll
        for (int i = 0; i < 4; i++) {
            const int kk = i >> 1;
            #pragma unroll
            for (int j = 0; j < 4; j++) {
                const float bv = bias[by * 128 + wn * 64 + j * 16 + ln];
                const size_t tile = (((size_t)(b * 8 + h) * 64 + kwin) * 4 + j) * 2 + kk;
                #pragma unroll
                for (int r = 0; r < 4; r++) {
                    const int klq = quad * 4 + r;
                    const int slot = ((i & 1) * 2 + (klq >> 3)) * 16 + ln;
                    const size_t idx = tile * 512 + slot * 8 + (klq & 7);
                    vTh[idx] = f2bf(acc[i][j][r] + bv);
                }
            }
        }
    }
}

// ---------- MFMA windowed attention: all operands pre-tiled; hi-only out ----
__global__ __launch_bounds__(256) void attn_mfma(
    const ushort_t* __restrict__ qTh, const ushort_t* __restrict__ qTl,
    const ushort_t* __restrict__ kTh, const ushort_t* __restrict__ kTl,
    const ushort_t* __restrict__ vTh,
    ushort_t* __restrict__ outh) {
    __shared__ __align__(16) ushort_t sKh[8 * 512];
    __shared__ __align__(16) ushort_t sKl[8 * 512];
    __shared__ __align__(16) ushort_t sV [8 * 512];
    __shared__ __align__(16) ushort_t sP [8 * 512];

    const int qs = blockIdx.x * 64;
    const int h = blockIdx.y, b = blockIdx.z;
    const int bh = b * 8 + h;
    const int tid = threadIdx.x, lane = tid & 63;
    const int w = tid >> 6, ln = lane & 15, quad = lane >> 4;
    const int lo8 = lane * 8;

    // Q fragments: direct global loads from A-frag tiles
    bf16x8 qf[2][2];
    {
        const size_t qt = ((size_t)bh * 256 + (qs >> 4) + w) * 2;
        qf[0][0] = *(const bf16x8*)(qTh + (qt + 0) * 512 + lo8);
        qf[1][0] = *(const bf16x8*)(qTh + (qt + 1) * 512 + lo8);
        qf[0][1] = *(const bf16x8*)(qTl + (qt + 0) * 512 + lo8);
        qf[1][1] = *(const bf16x8*)(qTl + (qt + 1) * 512 + lo8);
    }

    f32x4 oacc[4];
    const f32x4 zero = {0.f, 0.f, 0.f, 0.f};
    #pragma unroll
    for (int dt = 0; dt < 4; dt++) oacc[dt] = zero;
    float m_run[4], l_run[4];
    #pragma unroll
    for (int r = 0; r < 4; r++) { m_run[r] = -1e30f; l_run[r] = 0.f; }

    const float cscale = 0.125f * 1.44269504f;  // 1/sqrt(D) * log2(e)

    for (int kt = 0; kt < 5; kt++) {
        const int ks = qs - 128 + kt * 64;

        __syncthreads();  // prev iter's MFMA reads of sK/sV/sP done

        // stage K (jt = w) and V (dt = w), clamped tile indices
        {
            int st = (qs >> 4) - 8 + kt * 4 + w;
            st = st < 0 ? 0 : (st > 255 ? 255 : st);
            const size_t kb = ((size_t)bh * 256 + st) * 2 * 512 + lo8;
            gload16(kTh + kb,       &sKh[(w * 2 + 0) * 512]);
            gload16(kTh + kb + 512, &sKh[(w * 2 + 1) * 512]);
            gload16(kTl + kb,       &sKl[(w * 2 + 0) * 512]);
            gload16(kTl + kb + 512, &sKl[(w * 2 + 1) * 512]);
            int vw = (qs >> 6) - 2 + kt;
            vw = vw < 0 ? 0 : (vw > 63 ? 63 : vw);
            const size_t vb = (((size_t)bh * 64 + vw) * 4 + w) * 2 * 512 + lo8;
            gload16(vTh + vb,       &sV[(w * 2 + 0) * 512]);
            gload16(vTh + vb + 512, &sV[(w * 2 + 1) * 512]);
        }
        __syncthreads();  // staging visible

        // S = Q K^T (hh + hl + lh)
        f32x4 sacc[4];
        #pragma unroll
        for (int jt = 0; jt < 4; jt++) {
            f32x4 a = zero;
            const bool dead = (kt == 0 && jt < w) || (kt == 4 && jt > w) ||
                              (ks + 16 * jt >= L_SEQ) || (ks + 16 * jt + 15 < 0);
            if (!dead) {
                #pragma unroll
                for (int kk = 0; kk < 2; kk++) {
                    const bf16x8 kh = *(const bf16x8*)&sKh[(jt * 2 + kk) * 512 + lo8];
                    const bf16x8 klo = *(const bf16x8*)&sKl[(jt * 2 + kk) * 512 + lo8];
                    a = __builtin_amdgcn_mfma_f32_16x16x32_bf16(qf[kk][0], kh, a, 0, 0, 0);
                    a = __builtin_amdgcn_mfma_f32_16x16x32_bf16(qf[kk][0], klo, a, 0, 0, 0);
                    a = __builtin_amdgcn_mfma_f32_16x16x32_bf16(qf[kk][1], kh, a, 0, 0, 0);
                }
            }
            sacc[jt] = a;
        }

        // mask + online softmax (registers)
        float u[4][4];
        #pragma unroll
        for (int jt = 0; jt < 4; jt++) {
            const int kcol = ks + 16 * jt + ln;
            #pragma unroll
            for (int r = 0; r < 4; r++) {
                const int qrow = qs + 16 * w + quad * 4 + r;
                const int dist = qrow > kcol ? qrow - kcol : kcol - qrow;
                const bool ok = (kcol >= 0) && (kcol < L_SEQ) && (dist >= 1) && (dist <= WIN);
                u[jt][r] = ok ? sacc[jt][r] * cscale : -INFINITY;
            }
        }
        float mk[4];
        #pragma unroll
        for (int r = 0; r < 4; r++)
            mk[r] = fmaxf(fmaxf(u[0][r], u[1][r]), fmaxf(u[2][r], u[3][r]));
        #pragma unroll
        for (int off = 1; off <= 8; off <<= 1)
            #pragma unroll
            for (int r = 0; r < 4; r++)
                mk[r] = fmaxf(mk[r], __shfl_xor(mk[r], off));

        float alpha[4], psum[4], p[4][4];
        #pragma unroll
        for (int r = 0; r < 4; r++) {
            const float mnew = fmaxf(fmaxf(m_run[r], mk[r]), -1e30f);
            alpha[r] = exp2f(m_run[r] - mnew);
            m_run[r] = mnew;
            psum[r] = 0.f;
            #pragma unroll
            for (int jt = 0; jt < 4; jt++) {
                p[jt][r] = exp2f(u[jt][r] - mnew);
                psum[r] += p[jt][r];
            }
        }
        #pragma unroll
        for (int off = 1; off <= 8; off <<= 1)
            #pragma unroll
            for (int r = 0; r < 4; r++)
                psum[r] += __shfl_xor(psum[r], off);
        #pragma unroll
        for (int r = 0; r < 4; r++)
            l_run[r] = l_run[r] * alpha[r] + psum[r];

        #pragma unroll
        for (int dt = 0; dt < 4; dt++)
            #pragma unroll
            for (int r = 0; r < 4; r++)
                oacc[dt][r] *= alpha[r];

        // P (hi only): C-layout regs -> own wave's A-frag tile images in LDS
        #pragma unroll
        for (int jt = 0; jt < 4; jt++)
            #pragma unroll
            for (int r = 0; r < 4; r++) {
                const int slot = ((jt & 1) * 2 + (ln >> 3)) * 16 + quad * 4 + r;
                sP[w * 1024 + (jt >> 1) * 512 + slot * 8 + (ln & 7)] = f2bf(p[jt][r]);
            }
        // no barrier needed: PV reads only this wave's sP region + sV

        // O += P V (hi x hi)
        #pragma unroll
        for (int kk = 0; kk < 2; kk++) {
            const bf16x8 pf = *(const bf16x8*)&sP[w * 1024 + kk * 512 + lo8];
            #pragma unroll
            for (int dt = 0; dt < 4; dt++) {
                const bf16x8 vf = *(const bf16x8*)&sV[(dt * 2 + kk) * 512 + lo8];
                oacc[dt] = __builtin_amdgcn_mfma_f32_16x16x32_bf16(pf, vf, oacc[dt], 0, 0, 0);
            }
        }
    }

    // epilogue: write hi bf16 in GEMM2's A-frag tiled layout
    const int Rt = ((b * L_SEQ + qs) >> 4) + w;
    #pragma unroll
    for (int r = 0; r < 4; r++) {
        const float inv_l = 1.f / l_run[r];
        #pragma unroll
        for (int dt = 0; dt < 4; dt++) {
            const float v = oacc[dt][r] * inv_l;
            const int tile = Rt * 16 + h * 2 + (dt >> 1);
            const int slot = ((dt & 1) * 2 + (ln >> 3)) * 16 + quad * 4 + r;
            const size_t idx = (size_t)tile * 512 + slot * 8 + (ln & 7);
            outh[idx] = f2bf(v);
        }
    }
}

// ---------- GEMM2: out projection, 64x64 tile, grid (128, 8), 2-term ----------
// C = A_hi * (W_hi + W_lo)^T + bias   (A-lo dropped; error ~1.5e-3)
__global__ __launch_bounds__(256) void gemm_out(
    const ushort_t* __restrict__ Ah,
    const ushort_t* __restrict__ Wh, const ushort_t* __restrict__ Wl,
    const float* __restrict__ bias, float* __restrict__ C) {
    __shared__ __align__(16) ushort_t sAh[4 * 512];
    __shared__ __align__(16) ushort_t sWh[4 * 512];
    __shared__ __align__(16) ushort_t sWl[4 * 512];

    const int tid = threadIdx.x, lane = tid & 63, w = tid >> 6;
    const int wm = w & 1, wn = w >> 1, ln = lane & 15, quad = lane >> 4;
    const int bx = blockIdx.x, by = blockIdx.y;
    const int lo8 = lane * 8;

    f32x4 acc[2][2];
    const f32x4 zero = {0.f, 0.f, 0.f, 0.f};
    #pragma unroll
    for (int i = 0; i < 2; i++)
        #pragma unroll
        for (int j = 0; j < 2; j++) acc[i][j] = zero;

    // staging roles: w0 -> Ah[0..1], w1 -> Ah[2..3], w2 -> Wh[0..3], w3 -> Wl[0..3]
    const ushort_t* src = (w == 0 || w == 1) ? Ah : (w == 2) ? Wh : Wl;
    ushort_t* dst = (w == 0 || w == 1) ? sAh : (w == 2) ? sWh : sWl;
    const int t0 = (w == 1) ? 2 : 0;
    const int nT = (w < 2) ? 2 : 4;
    const size_t tbase = (size_t)((w < 2) ? bx : by) * 4 * 16;

    for (int kt = 0; kt < 16; kt++) {
        __syncthreads();
        #pragma unroll
        for (int t = 0; t < 4; t++)
            if (t < nT)
                gload16(src + (tbase + (size_t)(t0 + t) * 16 + kt) * 512 + lo8,
                        &dst[(t0 + t) * 512]);
        __syncthreads();

        bf16x8 fah[2];
        #pragma unroll
        for (int i = 0; i < 2; i++)
            fah[i] = *(const bf16x8*)&sAh[(wm * 2 + i) * 512 + lo8];
        #pragma unroll
        for (int j = 0; j < 2; j++) {
            const bf16x8 fbh = *(const bf16x8*)&sWh[(wn * 2 + j) * 512 + lo8];
            const bf16x8 fbl = *(const bf16x8*)&sWl[(wn * 2 + j) * 512 + lo8];
            #pragma unroll
            for (int i = 0; i < 2; i++) {
                acc[i][j] = __builtin_amdgcn_mfma_f32_16x16x32_bf16(fah[i], fbh, acc[i][j], 0, 0, 0);
                acc[i][j] = __builtin_amdgcn_mfma_f32_16x16x32_bf16(fah[i], fbl, acc[i][j], 0, 0, 0);
            }
        }
    }

    #pragma unroll
    for (int i = 0; i < 2; i++) {
        const int row0 = bx * 64 + wm * 32 + i * 16 + quad * 4;
        #pragma unroll
        for (int j = 0; j < 2; j++) {
            const int col = by * 64 + wn * 32 + j * 16 + ln;
            const float bv = bias[col];
            #pragma unroll
            for (int r = 0; r < 4; r++)
                C[(size_t)(row0 + r) * E_DIM + col] = acc[i][j][r] + bv;
        }
    }
}

extern "C" void kernel_launch(void* const* d_in, const int* in_sizes, int n_in,
                              void* d_out, int out_size, void* d_ws, size_t ws_size,
                              hipStream_t stream) {
    const float* x         = (const float*)d_in[0];
    const float* in_proj_w = (const float*)d_in[1];
    const float* in_proj_b = (const float*)d_in[2];
    const float* out_w     = (const float*)d_in[3];
    const float* out_b     = (const float*)d_in[4];
    float* out = (float*)d_out;

    const int N = B_SZ * L_SEQ;  // 8192
    const size_t NE = (size_t)N * E_DIM;  // 4.19M elems

    char* p = (char*)d_ws;
    ushort_t* w1h = (ushort_t*)p; p += (size_t)3 * E_DIM * E_DIM * 2;
    ushort_t* w1l = (ushort_t*)p; p += (size_t)3 * E_DIM * E_DIM * 2;
    ushort_t* w2h = (ushort_t*)p; p += (size_t)E_DIM * E_DIM * 2;
    ushort_t* w2l = (ushort_t*)p; p += (size_t)E_DIM * E_DIM * 2;
    ushort_t* qTh = (ushort_t*)p; p += NE * 2;
    ushort_t* qTl = (ushort_t*)p; p += NE * 2;
    ushort_t* kTh = (ushort_t*)p; p += NE * 2;
    ushort_t* kTl = (ushort_t*)p; p += NE * 2;
    ushort_t* vTh = (ushort_t*)p; p += NE * 2;
    ushort_t* ath = (ushort_t*)p; p += NE * 2;
    // total ~67 MB

    convertW<<<512, 256, 0, stream>>>(in_proj_w, w1h, w1l, out_w, w2h, w2l);

    gemm_qkv<<<dim3(64, 12), 256, 0, stream>>>(
        x, w1h, w1l, in_proj_b, qTh, qTl, kTh, kTl, vTh);

    attn_mfma<<<dim3(L_SEQ / 64, H_DIM, B_SZ), 256, 0, stream>>>(
        qTh, qTl, kTh, kTl, vTh, ath);

    gemm_out<<<dim3(128, 8), 256, 0, stream>>>(
        ath, w2h, w2l, out_b, out);
}

// Round 10
// 159.616 us; speedup vs baseline: 1.2681x; 1.2681x over previous
//
#include <hip/hip_runtime.h>
#include <math.h>

#define E_DIM 512
#define H_DIM 8
#define WIN 128
#define L_SEQ 4096
#define B_SZ 2

typedef unsigned short ushort_t;
typedef unsigned int uint_t;
typedef __attribute__((ext_vector_type(8))) __bf16 bf16x8;
typedef __attribute__((ext_vector_type(4))) float f32x4;

// ---------- bf16 helpers (manual, RNE) ----------
__device__ __forceinline__ ushort_t f2bf(float f) {
    uint_t u = __float_as_uint(f);
    u = u + 0x7fffu + ((u >> 16) & 1u);
    return (ushort_t)(u >> 16);
}
__device__ __forceinline__ float bf2f(ushort_t h) {
    return __uint_as_float((uint_t)h << 16);
}

__device__ __forceinline__ void gload16(const ushort_t* g, ushort_t* l) {
    __builtin_amdgcn_global_load_lds(
        (const __attribute__((address_space(1))) void*)g,
        (__attribute__((address_space(3))) void*)l,
        16, 0, 0);
}

// ===== Tile image (16 rows x 32 k = 512 elems = 1 KB) =====
// idx = slot*8 + (k&7), slot = ((k>>3)&3)*16 + (row&15)  [slot = quad*16+ln]
// A-frag & B-frag both read at lane*8 within a tile image.

// ---------- convert: x -> hi only; w1, w2 -> hi+lo (all tiled) ----------
// slot-groups: x 524288, w1 98304, w2 32768 -> 655360 total = 2560 blocks
__global__ __launch_bounds__(256) void convertX(
    const float* __restrict__ x,  ushort_t* __restrict__ xh,
    const float* __restrict__ w1, ushort_t* __restrict__ w1h, ushort_t* __restrict__ w1l,
    const float* __restrict__ w2, ushort_t* __restrict__ w2h, ushort_t* __restrict__ w2l) {
    int sg = blockIdx.x * 256 + threadIdx.x;
    const float* src; ushort_t* dh; ushort_t* dl; bool wantLo;
    if (sg < 524288)      { src = x;  dh = xh;  dl = nullptr; wantLo = false; }
    else if (sg < 622592) { src = w1; dh = w1h; dl = w1l; wantLo = true; sg -= 524288; }
    else                  { src = w2; dh = w2h; dl = w2l; wantLo = true; sg -= 622592; }
    const int tile = sg >> 6, slot = sg & 63;
    const int row = (tile >> 4) * 16 + (slot & 15);
    const int k   = (tile & 15) * 32 + (slot >> 4) * 8;
    const float4 v0 = *(const float4*)&src[(size_t)row * 512 + k];
    const float4 v1 = *(const float4*)&src[(size_t)row * 512 + k + 4];
    const float vv[8] = {v0.x, v0.y, v0.z, v0.w, v1.x, v1.y, v1.z, v1.w};
    union { ushort_t u[8]; ushort4 v[2]; } h, l;
    #pragma unroll
    for (int j = 0; j < 8; j++) {
        const ushort_t a = f2bf(vv[j]);
        h.u[j] = a;
        l.u[j] = f2bf(vv[j] - bf2f(a));
    }
    ((ushort4*)(dh + (size_t)sg * 8))[0] = h.v[0];
    ((ushort4*)(dh + (size_t)sg * 8))[1] = h.v[1];
    if (wantLo) {
        ((ushort4*)(dl + (size_t)sg * 8))[0] = l.v[0];
        ((ushort4*)(dl + (size_t)sg * 8))[1] = l.v[1];
    }
}

// ---------- GEMM1: qkv projection, 2-term (x-hi only) ----------
// 128x128 tile, BK=32, grid (64, 12). by<4: q, [4,8): k, >=8: v.
// Staging roles: w0/w1 -> A-hi tiles, w2 -> W-hi, w3 -> W-lo.
__global__ __launch_bounds__(256) void gemm_qkv(
    const ushort_t* __restrict__ Ah,
    const ushort_t* __restrict__ Wh, const ushort_t* __restrict__ Wl,
    const float* __restrict__ bias,
    ushort_t* __restrict__ qTh, ushort_t* __restrict__ qTl,
    ushort_t* __restrict__ kTh, ushort_t* __restrict__ kTl,
    ushort_t* __restrict__ vTh) {
    __shared__ __align__(16) ushort_t sAh[8 * 512];
    __shared__ __align__(16) ushort_t sWh[8 * 512];
    __shared__ __align__(16) ushort_t sWl[8 * 512];

    const int tid = threadIdx.x, lane = tid & 63, w = tid >> 6;
    const int wm = w & 1, wn = w >> 1, ln = lane & 15, quad = lane >> 4;
    const int bx = blockIdx.x, by = blockIdx.y;
    const int lo8 = lane * 8;

    f32x4 acc[4][4];
    const f32x4 zero = {0.f, 0.f, 0.f, 0.f};
    #pragma unroll
    for (int i = 0; i < 4; i++)
        #pragma unroll
        for (int j = 0; j < 4; j++) acc[i][j] = zero;

    // staging assignment (wave-uniform): w0/w1 A (4 tiles each), w2 Wh (8), w3 Wl (8)
    const ushort_t* src;
    ushort_t* dst;
    int t0, nT;
    size_t tbidx;
    if (w < 2) { src = Ah; dst = sAh; t0 = w * 4; nT = 4; tbidx = (size_t)bx * 8 + t0; }
    else       { src = (w == 2) ? Wh : Wl; dst = (w == 2) ? sWh : sWl; t0 = 0; nT = 8; tbidx = (size_t)by * 8; }
    const ushort_t* pb[8];
    #pragma unroll
    for (int t = 0; t < 8; t++)
        pb[t] = src + ((tbidx + (t < nT ? t : 0)) * 16) * 512;

    for (int kt = 0; kt < 16; kt++) {
        const int koff = kt * 512;
        __syncthreads();
        #pragma unroll
        for (int t = 0; t < 8; t++)
            if (t < nT)
                gload16(pb[t] + koff + lo8, &dst[(t0 + t) * 512]);
        __syncthreads();

        bf16x8 fah[4];
        #pragma unroll
        for (int i = 0; i < 4; i++)
            fah[i] = *(const bf16x8*)&sAh[(wm * 4 + i) * 512 + lo8];
        #pragma unroll
        for (int j = 0; j < 4; j++) {
            const bf16x8 fbh = *(const bf16x8*)&sWh[(wn * 4 + j) * 512 + lo8];
            const bf16x8 fbl = *(const bf16x8*)&sWl[(wn * 4 + j) * 512 + lo8];
            #pragma unroll
            for (int i = 0; i < 4; i++) {
                acc[i][j] = __builtin_amdgcn_mfma_f32_16x16x32_bf16(fah[i], fbh, acc[i][j], 0, 0, 0);
                acc[i][j] = __builtin_amdgcn_mfma_f32_16x16x32_bf16(fah[i], fbl, acc[i][j], 0, 0, 0);
            }
        }
    }

    // ---- epilogue: C/D layout col=ln (within j-tile), row=quad*4+r ----
    const int b = bx >> 5;               // batch
    const int h = 2 * (by & 3) + wn;     // head (wave-uniform)
    if (by < 8) {
        ushort_t* dh = (by < 4) ? qTh : kTh;
        ushort_t* dl = (by < 4) ? qTl : kTl;
        #pragma unroll
        for (int i = 0; i < 4; i++) {
            const int rt = (bx & 31) * 8 + wm * 4 + i;   // row-tile within batch
            const size_t tb = ((size_t)(b * 8 + h) * 256 + rt) * 2;
            #pragma unroll
            for (int j = 0; j < 4; j++) {
                const float bv = bias[by * 128 + wn * 64 + j * 16 + ln];
                const size_t tile = tb + (j >> 1);
                #pragma unroll
                for (int r = 0; r < 4; r++) {
                    const int slot = ((j * 2 + (ln >> 3)) & 3) * 16 + quad * 4 + r;
                    const size_t idx = tile * 512 + slot * 8 + (ln & 7);
                    const float v = acc[i][j][r] + bv;
                    const ushort_t hh = f2bf(v);
                    dh[idx] = hh;
                    dl[idx] = f2bf(v - bf2f(hh));
                }
            }
        }
    } else {
        // v: hi only, transposed tiles (rows = d, k = kseq)
        const int kwin = (bx & 31) * 2 + wm;
        #pragma unroll
        for (int i = 0; i < 4; i++) {
            const int kk = i >> 1;
            #pragma unroll
            for (int j = 0; j < 4; j++) {
                const float bv = bias[by * 128 + wn * 64 + j * 16 + ln];
                const size_t tile = (((size_t)(b * 8 + h) * 64 + kwin) * 4 + j) * 2 + kk;
                #pragma unroll
                for (int r = 0; r < 4; r++) {
                    const int klq = quad * 4 + r;
                    const int slot = ((i & 1) * 2 + (klq >> 3)) * 16 + ln;
                    const size_t idx = tile * 512 + slot * 8 + (klq & 7);
                    vTh[idx] = f2bf(acc[i][j][r] + bv);
                }
            }
        }
    }
}

// ---------- MFMA windowed attention: all operands pre-tiled; hi-only out ----
__global__ __launch_bounds__(256) void attn_mfma(
    const ushort_t* __restrict__ qTh, const ushort_t* __restrict__ qTl,
    const ushort_t* __restrict__ kTh, const ushort_t* __restrict__ kTl,
    const ushort_t* __restrict__ vTh,
    ushort_t* __restrict__ outh) {
    __shared__ __align__(16) ushort_t sKh[8 * 512];
    __shared__ __align__(16) ushort_t sKl[8 * 512];
    __shared__ __align__(16) ushort_t sV [8 * 512];
    __shared__ __align__(16) ushort_t sP [8 * 512];

    const int qs = blockIdx.x * 64;
    const int h = blockIdx.y, b = blockIdx.z;
    const int bh = b * 8 + h;
    const int tid = threadIdx.x, lane = tid & 63;
    const int w = tid >> 6, ln = lane & 15, quad = lane >> 4;
    const int lo8 = lane * 8;

    // Q fragments: direct global loads from A-frag tiles
    bf16x8 qf[2][2];
    {
        const size_t qt = ((size_t)bh * 256 + (qs >> 4) + w) * 2;
        qf[0][0] = *(const bf16x8*)(qTh + (qt + 0) * 512 + lo8);
        qf[1][0] = *(const bf16x8*)(qTh + (qt + 1) * 512 + lo8);
        qf[0][1] = *(const bf16x8*)(qTl + (qt + 0) * 512 + lo8);
        qf[1][1] = *(const bf16x8*)(qTl + (qt + 1) * 512 + lo8);
    }

    f32x4 oacc[4];
    const f32x4 zero = {0.f, 0.f, 0.f, 0.f};
    #pragma unroll
    for (int dt = 0; dt < 4; dt++) oacc[dt] = zero;
    float m_run[4], l_run[4];
    #pragma unroll
    for (int r = 0; r < 4; r++) { m_run[r] = -1e30f; l_run[r] = 0.f; }

    const float cscale = 0.125f * 1.44269504f;  // 1/sqrt(D) * log2(e)

    for (int kt = 0; kt < 5; kt++) {
        const int ks = qs - 128 + kt * 64;

        __syncthreads();  // prev iter's MFMA reads of sK/sV/sP done

        // stage K (jt = w) and V (dt = w), clamped tile indices
        {
            int st = (qs >> 4) - 8 + kt * 4 + w;
            st = st < 0 ? 0 : (st > 255 ? 255 : st);
            const size_t kb = ((size_t)bh * 256 + st) * 2 * 512 + lo8;
            gload16(kTh + kb,       &sKh[(w * 2 + 0) * 512]);
            gload16(kTh + kb + 512, &sKh[(w * 2 + 1) * 512]);
            gload16(kTl + kb,       &sKl[(w * 2 + 0) * 512]);
            gload16(kTl + kb + 512, &sKl[(w * 2 + 1) * 512]);
            int vw = (qs >> 6) - 2 + kt;
            vw = vw < 0 ? 0 : (vw > 63 ? 63 : vw);
            const size_t vb = (((size_t)bh * 64 + vw) * 4 + w) * 2 * 512 + lo8;
            gload16(vTh + vb,       &sV[(w * 2 + 0) * 512]);
            gload16(vTh + vb + 512, &sV[(w * 2 + 1) * 512]);
        }
        __syncthreads();  // staging visible

        // S = Q K^T (hh + hl + lh)
        f32x4 sacc[4];
        #pragma unroll
        for (int jt = 0; jt < 4; jt++) {
            f32x4 a = zero;
            const bool dead = (kt == 0 && jt < w) || (kt == 4 && jt > w) ||
                              (ks + 16 * jt >= L_SEQ) || (ks + 16 * jt + 15 < 0);
            if (!dead) {
                #pragma unroll
                for (int kk = 0; kk < 2; kk++) {
                    const bf16x8 kh = *(const bf16x8*)&sKh[(jt * 2 + kk) * 512 + lo8];
                    const bf16x8 klo = *(const bf16x8*)&sKl[(jt * 2 + kk) * 512 + lo8];
                    a = __builtin_amdgcn_mfma_f32_16x16x32_bf16(qf[kk][0], kh, a, 0, 0, 0);
                    a = __builtin_amdgcn_mfma_f32_16x16x32_bf16(qf[kk][0], klo, a, 0, 0, 0);
                    a = __builtin_amdgcn_mfma_f32_16x16x32_bf16(qf[kk][1], kh, a, 0, 0, 0);
                }
            }
            sacc[jt] = a;
        }

        // mask + online softmax (registers)
        float u[4][4];
        #pragma unroll
        for (int jt = 0; jt < 4; jt++) {
            const int kcol = ks + 16 * jt + ln;
            #pragma unroll
            for (int r = 0; r < 4; r++) {
                const int qrow = qs + 16 * w + quad * 4 + r;
                const int dist = qrow > kcol ? qrow - kcol : kcol - qrow;
                const bool ok = (kcol >= 0) && (kcol < L_SEQ) && (dist >= 1) && (dist <= WIN);
                u[jt][r] = ok ? sacc[jt][r] * cscale : -INFINITY;
            }
        }
        float mk[4];
        #pragma unroll
        for (int r = 0; r < 4; r++)
            mk[r] = fmaxf(fmaxf(u[0][r], u[1][r]), fmaxf(u[2][r], u[3][r]));
        #pragma unroll
        for (int off = 1; off <= 8; off <<= 1)
            #pragma unroll
            for (int r = 0; r < 4; r++)
                mk[r] = fmaxf(mk[r], __shfl_xor(mk[r], off));

        float alpha[4], psum[4], p[4][4];
        #pragma unroll
        for (int r = 0; r < 4; r++) {
            const float mnew = fmaxf(fmaxf(m_run[r], mk[r]), -1e30f);
            alpha[r] = exp2f(m_run[r] - mnew);
            m_run[r] = mnew;
            psum[r] = 0.f;
            #pragma unroll
            for (int jt = 0; jt < 4; jt++) {
                p[jt][r] = exp2f(u[jt][r] - mnew);
                psum[r] += p[jt][r];
            }
        }
        #pragma unroll
        for (int off = 1; off <= 8; off <<= 1)
            #pragma unroll
            for (int r = 0; r < 4; r++)
                psum[r] += __shfl_xor(psum[r], off);
        #pragma unroll
        for (int r = 0; r < 4; r++)
            l_run[r] = l_run[r] * alpha[r] + psum[r];

        #pragma unroll
        for (int dt = 0; dt < 4; dt++)
            #pragma unroll
            for (int r = 0; r < 4; r++)
                oacc[dt][r] *= alpha[r];

        // P (hi only): C-layout regs -> own wave's A-frag tile images in LDS
        #pragma unroll
        for (int jt = 0; jt < 4; jt++)
            #pragma unroll
            for (int r = 0; r < 4; r++) {
                const int slot = ((jt & 1) * 2 + (ln >> 3)) * 16 + quad * 4 + r;
                sP[w * 1024 + (jt >> 1) * 512 + slot * 8 + (ln & 7)] = f2bf(p[jt][r]);
            }
        // no barrier needed: PV reads only this wave's sP region + sV

        // O += P V (hi x hi)
        #pragma unroll
        for (int kk = 0; kk < 2; kk++) {
            const bf16x8 pf = *(const bf16x8*)&sP[w * 1024 + kk * 512 + lo8];
            #pragma unroll
            for (int dt = 0; dt < 4; dt++) {
                const bf16x8 vf = *(const bf16x8*)&sV[(dt * 2 + kk) * 512 + lo8];
                oacc[dt] = __builtin_amdgcn_mfma_f32_16x16x32_bf16(pf, vf, oacc[dt], 0, 0, 0);
            }
        }
    }

    // epilogue: write hi bf16 in GEMM2's A-frag tiled layout
    const int Rt = ((b * L_SEQ + qs) >> 4) + w;
    #pragma unroll
    for (int r = 0; r < 4; r++) {
        const float inv_l = 1.f / l_run[r];
        #pragma unroll
        for (int dt = 0; dt < 4; dt++) {
            const float v = oacc[dt][r] * inv_l;
            const int tile = Rt * 16 + h * 2 + (dt >> 1);
            const int slot = ((dt & 1) * 2 + (ln >> 3)) * 16 + quad * 4 + r;
            const size_t idx = (size_t)tile * 512 + slot * 8 + (ln & 7);
            outh[idx] = f2bf(v);
        }
    }
}

// ---------- GEMM2: out projection, 64x64 tile, grid (128, 8), 2-term ----------
__global__ __launch_bounds__(256) void gemm_out(
    const ushort_t* __restrict__ Ah,
    const ushort_t* __restrict__ Wh, const ushort_t* __restrict__ Wl,
    const float* __restrict__ bias, float* __restrict__ C) {
    __shared__ __align__(16) ushort_t sAh[4 * 512];
    __shared__ __align__(16) ushort_t sWh[4 * 512];
    __shared__ __align__(16) ushort_t sWl[4 * 512];

    const int tid = threadIdx.x, lane = tid & 63, w = tid >> 6;
    const int wm = w & 1, wn = w >> 1, ln = lane & 15, quad = lane >> 4;
    const int bx = blockIdx.x, by = blockIdx.y;
    const int lo8 = lane * 8;

    f32x4 acc[2][2];
    const f32x4 zero = {0.f, 0.f, 0.f, 0.f};
    #pragma unroll
    for (int i = 0; i < 2; i++)
        #pragma unroll
        for (int j = 0; j < 2; j++) acc[i][j] = zero;

    // staging roles: w0 -> Ah[0..1], w1 -> Ah[2..3], w2 -> Wh[0..3], w3 -> Wl[0..3]
    const ushort_t* src = (w == 0 || w == 1) ? Ah : (w == 2) ? Wh : Wl;
    ushort_t* dst = (w == 0 || w == 1) ? sAh : (w == 2) ? sWh : sWl;
    const int t0 = (w == 1) ? 2 : 0;
    const int nT = (w < 2) ? 2 : 4;
    const size_t tbase = (size_t)((w < 2) ? bx : by) * 4 * 16;

    for (int kt = 0; kt < 16; kt++) {
        __syncthreads();
        #pragma unroll
        for (int t = 0; t < 4; t++)
            if (t < nT)
                gload16(src + (tbase + (size_t)(t0 + t) * 16 + kt) * 512 + lo8,
                        &dst[(t0 + t) * 512]);
        __syncthreads();

        bf16x8 fah[2];
        #pragma unroll
        for (int i = 0; i < 2; i++)
            fah[i] = *(const bf16x8*)&sAh[(wm * 2 + i) * 512 + lo8];
        #pragma unroll
        for (int j = 0; j < 2; j++) {
            const bf16x8 fbh = *(const bf16x8*)&sWh[(wn * 2 + j) * 512 + lo8];
            const bf16x8 fbl = *(const bf16x8*)&sWl[(wn * 2 + j) * 512 + lo8];
            #pragma unroll
            for (int i = 0; i < 2; i++) {
                acc[i][j] = __builtin_amdgcn_mfma_f32_16x16x32_bf16(fah[i], fbh, acc[i][j], 0, 0, 0);
                acc[i][j] = __builtin_amdgcn_mfma_f32_16x16x32_bf16(fah[i], fbl, acc[i][j], 0, 0, 0);
            }
        }
    }

    #pragma unroll
    for (int i = 0; i < 2; i++) {
        const int row0 = bx * 64 + wm * 32 + i * 16 + quad * 4;
        #pragma unroll
        for (int j = 0; j < 2; j++) {
            const int col = by * 64 + wn * 32 + j * 16 + ln;
            const float bv = bias[col];
            #pragma unroll
            for (int r = 0; r < 4; r++)
                C[(size_t)(row0 + r) * E_DIM + col] = acc[i][j][r] + bv;
        }
    }
}

extern "C" void kernel_launch(void* const* d_in, const int* in_sizes, int n_in,
                              void* d_out, int out_size, void* d_ws, size_t ws_size,
                              hipStream_t stream) {
    const float* x         = (const float*)d_in[0];
    const float* in_proj_w = (const float*)d_in[1];
    const float* in_proj_b = (const float*)d_in[2];
    const float* out_w     = (const float*)d_in[3];
    const float* out_b     = (const float*)d_in[4];
    float* out = (float*)d_out;

    const int N = B_SZ * L_SEQ;  // 8192
    const size_t NE = (size_t)N * E_DIM;  // 4.19M elems

    char* p = (char*)d_ws;
    ushort_t* xh  = (ushort_t*)p; p += NE * 2;
    ushort_t* w1h = (ushort_t*)p; p += (size_t)3 * E_DIM * E_DIM * 2;
    ushort_t* w1l = (ushort_t*)p; p += (size_t)3 * E_DIM * E_DIM * 2;
    ushort_t* w2h = (ushort_t*)p; p += (size_t)E_DIM * E_DIM * 2;
    ushort_t* w2l = (ushort_t*)p; p += (size_t)E_DIM * E_DIM * 2;
    ushort_t* qTh = (ushort_t*)p; p += NE * 2;
    ushort_t* qTl = (ushort_t*)p; p += NE * 2;
    ushort_t* kTh = (ushort_t*)p; p += NE * 2;
    ushort_t* kTl = (ushort_t*)p; p += NE * 2;
    ushort_t* vTh = (ushort_t*)p; p += NE * 2;
    ushort_t* ath = (ushort_t*)p; p += NE * 2;
    // total ~63 MB

    convertX<<<2560, 256, 0, stream>>>(x, xh, in_proj_w, w1h, w1l, out_w, w2h, w2l);

    gemm_qkv<<<dim3(64, 12), 256, 0, stream>>>(
        xh, w1h, w1l, in_proj_b, qTh, qTl, kTh, kTl, vTh);

    attn_mfma<<<dim3(L_SEQ / 64, H_DIM, B_SZ), 256, 0, stream>>>(
        qTh, qTl, kTh, kTl, vTh, ath);

    gemm_out<<<dim3(128, 8), 256, 0, stream>>>(
        ath, w2h, w2l, out_b, out);
}

// Round 11
// 158.815 us; speedup vs baseline: 1.2745x; 1.0050x over previous
//
#include <hip/hip_runtime.h>
#include <math.h>

#define E_DIM 512
#define H_DIM 8
#define WIN 128
#define L_SEQ 4096
#define B_SZ 2

typedef unsigned short ushort_t;
typedef unsigned int uint_t;
typedef __attribute__((ext_vector_type(8))) __bf16 bf16x8;
typedef __attribute__((ext_vector_type(4))) float f32x4;

// ---------- bf16 helpers (manual, RNE) ----------
__device__ __forceinline__ ushort_t f2bf(float f) {
    uint_t u = __float_as_uint(f);
    u = u + 0x7fffu + ((u >> 16) & 1u);
    return (ushort_t)(u >> 16);
}
__device__ __forceinline__ float bf2f(ushort_t h) {
    return __uint_as_float((uint_t)h << 16);
}

__device__ __forceinline__ void gload16(const ushort_t* g, ushort_t* l) {
    __builtin_amdgcn_global_load_lds(
        (const __attribute__((address_space(1))) void*)g,
        (__attribute__((address_space(3))) void*)l,
        16, 0, 0);
}

// ===== Tile image (16 rows x 32 k = 512 elems = 1 KB) =====
// idx = slot*8 + (k&7), slot = ((k>>3)&3)*16 + (row&15)  [slot = quad*16+ln]
// A-frag & B-frag both read at lane*8 within a tile image.

// ---------- convert: x -> hi only; w1, w2 -> hi+lo (all tiled) ----------
__global__ __launch_bounds__(256) void convertX(
    const float* __restrict__ x,  ushort_t* __restrict__ xh,
    const float* __restrict__ w1, ushort_t* __restrict__ w1h, ushort_t* __restrict__ w1l,
    const float* __restrict__ w2, ushort_t* __restrict__ w2h, ushort_t* __restrict__ w2l) {
    int sg = blockIdx.x * 256 + threadIdx.x;
    const float* src; ushort_t* dh; ushort_t* dl; bool wantLo;
    if (sg < 524288)      { src = x;  dh = xh;  dl = nullptr; wantLo = false; }
    else if (sg < 622592) { src = w1; dh = w1h; dl = w1l; wantLo = true; sg -= 524288; }
    else                  { src = w2; dh = w2h; dl = w2l; wantLo = true; sg -= 622592; }
    const int tile = sg >> 6, slot = sg & 63;
    const int row = (tile >> 4) * 16 + (slot & 15);
    const int k   = (tile & 15) * 32 + (slot >> 4) * 8;
    const float4 v0 = *(const float4*)&src[(size_t)row * 512 + k];
    const float4 v1 = *(const float4*)&src[(size_t)row * 512 + k + 4];
    const float vv[8] = {v0.x, v0.y, v0.z, v0.w, v1.x, v1.y, v1.z, v1.w};
    union { ushort_t u[8]; ushort4 v[2]; } h, l;
    #pragma unroll
    for (int j = 0; j < 8; j++) {
        const ushort_t a = f2bf(vv[j]);
        h.u[j] = a;
        l.u[j] = f2bf(vv[j] - bf2f(a));
    }
    ((ushort4*)(dh + (size_t)sg * 8))[0] = h.v[0];
    ((ushort4*)(dh + (size_t)sg * 8))[1] = h.v[1];
    if (wantLo) {
        ((ushort4*)(dl + (size_t)sg * 8))[0] = l.v[0];
        ((ushort4*)(dl + (size_t)sg * 8))[1] = l.v[1];
    }
}

// ---------- GEMM1: qkv projection, 2-term (x-hi only), BK=64 ----------
// 128x128 tile, grid (64, 12). by<4: q, [4,8): k, >=8: v.
// 8 K-iterations; 48 tile-loads/iter balanced 12 per wave; 64 MFMA/wave/iter.
__global__ __launch_bounds__(256) void gemm_qkv(
    const ushort_t* __restrict__ Ah,
    const ushort_t* __restrict__ Wh, const ushort_t* __restrict__ Wl,
    const float* __restrict__ bias,
    ushort_t* __restrict__ qTh, ushort_t* __restrict__ qTl,
    ushort_t* __restrict__ kTh, ushort_t* __restrict__ kTl,
    ushort_t* __restrict__ vTh) {
    __shared__ __align__(16) ushort_t sAh[16 * 512];
    __shared__ __align__(16) ushort_t sWh[16 * 512];
    __shared__ __align__(16) ushort_t sWl[16 * 512];

    const int tid = threadIdx.x, lane = tid & 63, w = tid >> 6;
    const int wm = w & 1, wn = w >> 1, ln = lane & 15, quad = lane >> 4;
    const int bx = blockIdx.x, by = blockIdx.y;
    const int lo8 = lane * 8;
    const int wu = __builtin_amdgcn_readfirstlane(w);

    f32x4 acc[4][4];
    const f32x4 zero = {0.f, 0.f, 0.f, 0.f};
    #pragma unroll
    for (int i = 0; i < 4; i++)
        #pragma unroll
        for (int j = 0; j < 4; j++) acc[i][j] = zero;

    // staging: 48 tiles (A: rt0..7 x ks0..1, Wh: ct0..7 x ks0..1, Wl same),
    // balanced 12 per wave; LDS slot g*512 within each array.
    const ushort_t* pb[12];
    ushort_t* db[12];
    #pragma unroll
    for (int t = 0; t < 12; t++) {
        const int g = wu * 12 + t;
        if (g < 16) {
            pb[t] = Ah + ((size_t)(bx * 8 + (g >> 1)) * 16 + (g & 1)) * 512;
            db[t] = &sAh[g * 512];
        } else if (g < 32) {
            const int u = g - 16;
            pb[t] = Wh + ((size_t)(by * 8 + (u >> 1)) * 16 + (u & 1)) * 512;
            db[t] = &sWh[u * 512];
        } else {
            const int u = g - 32;
            pb[t] = Wl + ((size_t)(by * 8 + (u >> 1)) * 16 + (u & 1)) * 512;
            db[t] = &sWl[u * 512];
        }
    }

    for (int KT = 0; KT < 8; KT++) {
        const int koff = KT * 1024;  // advance 2 k-subtiles
        __syncthreads();
        #pragma unroll
        for (int t = 0; t < 12; t++)
            gload16(pb[t] + koff + lo8, db[t]);
        __syncthreads();

        #pragma unroll
        for (int ks = 0; ks < 2; ks++) {
            bf16x8 fah[4];
            #pragma unroll
            for (int i = 0; i < 4; i++)
                fah[i] = *(const bf16x8*)&sAh[((wm * 4 + i) * 2 + ks) * 512 + lo8];
            #pragma unroll
            for (int j = 0; j < 4; j++) {
                const bf16x8 fbh = *(const bf16x8*)&sWh[((wn * 4 + j) * 2 + ks) * 512 + lo8];
                const bf16x8 fbl = *(const bf16x8*)&sWl[((wn * 4 + j) * 2 + ks) * 512 + lo8];
                #pragma unroll
                for (int i = 0; i < 4; i++) {
                    acc[i][j] = __builtin_amdgcn_mfma_f32_16x16x32_bf16(fah[i], fbh, acc[i][j], 0, 0, 0);
                    acc[i][j] = __builtin_amdgcn_mfma_f32_16x16x32_bf16(fah[i], fbl, acc[i][j], 0, 0, 0);
                }
            }
        }
    }

    // ---- epilogue: C/D layout col=ln (within j-tile), row=quad*4+r ----
    const int b = bx >> 5;               // batch
    const int h = 2 * (by & 3) + wn;     // head (wave-uniform)
    if (by < 8) {
        ushort_t* dh = (by < 4) ? qTh : kTh;
        ushort_t* dl = (by < 4) ? qTl : kTl;
        #pragma unroll
        for (int i = 0; i < 4; i++) {
            const int rt = (bx & 31) * 8 + wm * 4 + i;   // row-tile within batch
            const size_t tb = ((size_t)(b * 8 + h) * 256 + rt) * 2;
            #pragma unroll
            for (int j = 0; j < 4; j++) {
                const float bv = bias[by * 128 + wn * 64 + j * 16 + ln];
                const size_t tile = tb + (j >> 1);
                #pragma unroll
                for (int r = 0; r < 4; r++) {
                    const int slot = ((j * 2 + (ln >> 3)) & 3) * 16 + quad * 4 + r;
                    const size_t idx = tile * 512 + slot * 8 + (ln & 7);
                    const float v = acc[i][j][r] + bv;
                    const ushort_t hh = f2bf(v);
                    dh[idx] = hh;
                    dl[idx] = f2bf(v - bf2f(hh));
                }
            }
        }
    } else {
        // v: hi only, transposed tiles (rows = d, k = kseq)
        const int kwin = (bx & 31) * 2 + wm;
        #pragma unroll
        for (int i = 0; i < 4; i++) {
            const int kk = i >> 1;
            #pragma unroll
            for (int j = 0; j < 4; j++) {
                const float bv = bias[by * 128 + wn * 64 + j * 16 + ln];
                const size_t tile = (((size_t)(b * 8 + h) * 64 + kwin) * 4 + j) * 2 + kk;
                #pragma unroll
                for (int r = 0; r < 4; r++) {
                    const int klq = quad * 4 + r;
                    const int slot = ((i & 1) * 2 + (klq >> 3)) * 16 + ln;
                    const size_t idx = tile * 512 + slot * 8 + (klq & 7);
                    vTh[idx] = f2bf(acc[i][j][r] + bv);
                }
            }
        }
    }
}

// ---------- MFMA windowed attention: all operands pre-tiled; hi-only out ----
__global__ __launch_bounds__(256) void attn_mfma(
    const ushort_t* __restrict__ qTh, const ushort_t* __restrict__ qTl,
    const ushort_t* __restrict__ kTh, const ushort_t* __restrict__ kTl,
    const ushort_t* __restrict__ vTh,
    ushort_t* __restrict__ outh) {
    __shared__ __align__(16) ushort_t sKh[8 * 512];
    __shared__ __align__(16) ushort_t sKl[8 * 512];
    __shared__ __align__(16) ushort_t sV [8 * 512];
    __shared__ __align__(16) ushort_t sP [8 * 512];

    const int qs = blockIdx.x * 64;
    const int h = blockIdx.y, b = blockIdx.z;
    const int bh = b * 8 + h;
    const int tid = threadIdx.x, lane = tid & 63;
    const int w = tid >> 6, ln = lane & 15, quad = lane >> 4;
    const int lo8 = lane * 8;

    // Q fragments: direct global loads from A-frag tiles
    bf16x8 qf[2][2];
    {
        const size_t qt = ((size_t)bh * 256 + (qs >> 4) + w) * 2;
        qf[0][0] = *(const bf16x8*)(qTh + (qt + 0) * 512 + lo8);
        qf[1][0] = *(const bf16x8*)(qTh + (qt + 1) * 512 + lo8);
        qf[0][1] = *(const bf16x8*)(qTl + (qt + 0) * 512 + lo8);
        qf[1][1] = *(const bf16x8*)(qTl + (qt + 1) * 512 + lo8);
    }

    f32x4 oacc[4];
    const f32x4 zero = {0.f, 0.f, 0.f, 0.f};
    #pragma unroll
    for (int dt = 0; dt < 4; dt++) oacc[dt] = zero;
    float m_run[4], l_run[4];
    #pragma unroll
    for (int r = 0; r < 4; r++) { m_run[r] = -1e30f; l_run[r] = 0.f; }

    const float cscale = 0.125f * 1.44269504f;  // 1/sqrt(D) * log2(e)

    for (int kt = 0; kt < 5; kt++) {
        const int ks = qs - 128 + kt * 64;

        __syncthreads();  // prev iter's MFMA reads of sK/sV/sP done

        // stage K (jt = w) and V (dt = w), clamped tile indices
        {
            int st = (qs >> 4) - 8 + kt * 4 + w;
            st = st < 0 ? 0 : (st > 255 ? 255 : st);
            const size_t kb = ((size_t)bh * 256 + st) * 2 * 512 + lo8;
            gload16(kTh + kb,       &sKh[(w * 2 + 0) * 512]);
            gload16(kTh + kb + 512, &sKh[(w * 2 + 1) * 512]);
            gload16(kTl + kb,       &sKl[(w * 2 + 0) * 512]);
            gload16(kTl + kb + 512, &sKl[(w * 2 + 1) * 512]);
            int vw = (qs >> 6) - 2 + kt;
            vw = vw < 0 ? 0 : (vw > 63 ? 63 : vw);
            const size_t vb = (((size_t)bh * 64 + vw) * 4 + w) * 2 * 512 + lo8;
            gload16(vTh + vb,       &sV[(w * 2 + 0) * 512]);
            gload16(vTh + vb + 512, &sV[(w * 2 + 1) * 512]);
        }
        __syncthreads();  // staging visible

        // S = Q K^T (hh + hl + lh)
        f32x4 sacc[4];
        #pragma unroll
        for (int jt = 0; jt < 4; jt++) {
            f32x4 a = zero;
            const bool dead = (kt == 0 && jt < w) || (kt == 4 && jt > w) ||
                              (ks + 16 * jt >= L_SEQ) || (ks + 16 * jt + 15 < 0);
            if (!dead) {
                #pragma unroll
                for (int kk = 0; kk < 2; kk++) {
                    const bf16x8 kh = *(const bf16x8*)&sKh[(jt * 2 + kk) * 512 + lo8];
                    const bf16x8 klo = *(const bf16x8*)&sKl[(jt * 2 + kk) * 512 + lo8];
                    a = __builtin_amdgcn_mfma_f32_16x16x32_bf16(qf[kk][0], kh, a, 0, 0, 0);
                    a = __builtin_amdgcn_mfma_f32_16x16x32_bf16(qf[kk][0], klo, a, 0, 0, 0);
                    a = __builtin_amdgcn_mfma_f32_16x16x32_bf16(qf[kk][1], kh, a, 0, 0, 0);
                }
            }
            sacc[jt] = a;
        }

        // mask + online softmax (registers)
        float u[4][4];
        #pragma unroll
        for (int jt = 0; jt < 4; jt++) {
            const int kcol = ks + 16 * jt + ln;
            #pragma unroll
            for (int r = 0; r < 4; r++) {
                const int qrow = qs + 16 * w + quad * 4 + r;
                const int dist = qrow > kcol ? qrow - kcol : kcol - qrow;
                const bool ok = (kcol >= 0) && (kcol < L_SEQ) && (dist >= 1) && (dist <= WIN);
                u[jt][r] = ok ? sacc[jt][r] * cscale : -INFINITY;
            }
        }
        float mk[4];
        #pragma unroll
        for (int r = 0; r < 4; r++)
            mk[r] = fmaxf(fmaxf(u[0][r], u[1][r]), fmaxf(u[2][r], u[3][r]));
        #pragma unroll
        for (int off = 1; off <= 8; off <<= 1)
            #pragma unroll
            for (int r = 0; r < 4; r++)
                mk[r] = fmaxf(mk[r], __shfl_xor(mk[r], off));

        float alpha[4], psum[4], p[4][4];
        #pragma unroll
        for (int r = 0; r < 4; r++) {
            const float mnew = fmaxf(fmaxf(m_run[r], mk[r]), -1e30f);
            alpha[r] = exp2f(m_run[r] - mnew);
            m_run[r] = mnew;
            psum[r] = 0.f;
            #pragma unroll
            for (int jt = 0; jt < 4; jt++) {
                p[jt][r] = exp2f(u[jt][r] - mnew);
                psum[r] += p[jt][r];
            }
        }
        #pragma unroll
        for (int off = 1; off <= 8; off <<= 1)
            #pragma unroll
            for (int r = 0; r < 4; r++)
                psum[r] += __shfl_xor(psum[r], off);
        #pragma unroll
        for (int r = 0; r < 4; r++)
            l_run[r] = l_run[r] * alpha[r] + psum[r];

        #pragma unroll
        for (int dt = 0; dt < 4; dt++)
            #pragma unroll
            for (int r = 0; r < 4; r++)
                oacc[dt][r] *= alpha[r];

        // P (hi only): C-layout regs -> own wave's A-frag tile images in LDS
        #pragma unroll
        for (int jt = 0; jt < 4; jt++)
            #pragma unroll
            for (int r = 0; r < 4; r++) {
                const int slot = ((jt & 1) * 2 + (ln >> 3)) * 16 + quad * 4 + r;
                sP[w * 1024 + (jt >> 1) * 512 + slot * 8 + (ln & 7)] = f2bf(p[jt][r]);
            }
        // no barrier needed: PV reads only this wave's sP region + sV

        // O += P V (hi x hi)
        #pragma unroll
        for (int kk = 0; kk < 2; kk++) {
            const bf16x8 pf = *(const bf16x8*)&sP[w * 1024 + kk * 512 + lo8];
            #pragma unroll
            for (int dt = 0; dt < 4; dt++) {
                const bf16x8 vf = *(const bf16x8*)&sV[(dt * 2 + kk) * 512 + lo8];
                oacc[dt] = __builtin_amdgcn_mfma_f32_16x16x32_bf16(pf, vf, oacc[dt], 0, 0, 0);
            }
        }
    }

    // epilogue: write hi bf16 in GEMM2's A-frag tiled layout
    const int Rt = ((b * L_SEQ + qs) >> 4) + w;
    #pragma unroll
    for (int r = 0; r < 4; r++) {
        const float inv_l = 1.f / l_run[r];
        #pragma unroll
        for (int dt = 0; dt < 4; dt++) {
            const float v = oacc[dt][r] * inv_l;
            const int tile = Rt * 16 + h * 2 + (dt >> 1);
            const int slot = ((dt & 1) * 2 + (ln >> 3)) * 16 + quad * 4 + r;
            const size_t idx = (size_t)tile * 512 + slot * 8 + (ln & 7);
            outh[idx] = f2bf(v);
        }
    }
}

// ---------- GEMM2: out projection, 64x64 tile, BK=64, grid (128, 8) ----------
// 8 K-iterations; 24 tile-loads/iter balanced 6 per wave; 16 MFMA/wave/iter.
__global__ __launch_bounds__(256) void gemm_out(
    const ushort_t* __restrict__ Ah,
    const ushort_t* __restrict__ Wh, const ushort_t* __restrict__ Wl,
    const float* __restrict__ bias, float* __restrict__ C) {
    __shared__ __align__(16) ushort_t sAh[8 * 512];
    __shared__ __align__(16) ushort_t sWh[8 * 512];
    __shared__ __align__(16) ushort_t sWl[8 * 512];

    const int tid = threadIdx.x, lane = tid & 63, w = tid >> 6;
    const int wm = w & 1, wn = w >> 1, ln = lane & 15, quad = lane >> 4;
    const int bx = blockIdx.x, by = blockIdx.y;
    const int lo8 = lane * 8;
    const int wu = __builtin_amdgcn_readfirstlane(w);

    f32x4 acc[2][2];
    const f32x4 zero = {0.f, 0.f, 0.f, 0.f};
    #pragma unroll
    for (int i = 0; i < 2; i++)
        #pragma unroll
        for (int j = 0; j < 2; j++) acc[i][j] = zero;

    // staging: 24 tiles (A: rt0..3 x ks0..1, Wh: ct0..3 x ks0..1, Wl same),
    // balanced 6 per wave.
    const ushort_t* pb[6];
    ushort_t* db[6];
    #pragma unroll
    for (int t = 0; t < 6; t++) {
        const int g = wu * 6 + t;
        if (g < 8) {
            pb[t] = Ah + ((size_t)(bx * 4 + (g >> 1)) * 16 + (g & 1)) * 512;
            db[t] = &sAh[g * 512];
        } else if (g < 16) {
            const int u = g - 8;
            pb[t] = Wh + ((size_t)(by * 4 + (u >> 1)) * 16 + (u & 1)) * 512;
            db[t] = &sWh[u * 512];
        } else {
            const int u = g - 16;
            pb[t] = Wl + ((size_t)(by * 4 + (u >> 1)) * 16 + (u & 1)) * 512;
            db[t] = &sWl[u * 512];
        }
    }

    for (int KT = 0; KT < 8; KT++) {
        const int koff = KT * 1024;
        __syncthreads();
        #pragma unroll
        for (int t = 0; t < 6; t++)
            gload16(pb[t] + koff + lo8, db[t]);
        __syncthreads();

        #pragma unroll
        for (int ks = 0; ks < 2; ks++) {
            bf16x8 fah[2];
            #pragma unroll
            for (int i = 0; i < 2; i++)
                fah[i] = *(const bf16x8*)&sAh[((wm * 2 + i) * 2 + ks) * 512 + lo8];
            #pragma unroll
            for (int j = 0; j < 2; j++) {
                const bf16x8 fbh = *(const bf16x8*)&sWh[((wn * 2 + j) * 2 + ks) * 512 + lo8];
                const bf16x8 fbl = *(const bf16x8*)&sWl[((wn * 2 + j) * 2 + ks) * 512 + lo8];
                #pragma unroll
                for (int i = 0; i < 2; i++) {
                    acc[i][j] = __builtin_amdgcn_mfma_f32_16x16x32_bf16(fah[i], fbh, acc[i][j], 0, 0, 0);
                    acc[i][j] = __builtin_amdgcn_mfma_f32_16x16x32_bf16(fah[i], fbl, acc[i][j], 0, 0, 0);
                }
            }
        }
    }

    #pragma unroll
    for (int i = 0; i < 2; i++) {
        const int row0 = bx * 64 + wm * 32 + i * 16 + quad * 4;
        #pragma unroll
        for (int j = 0; j < 2; j++) {
            const int col = by * 64 + wn * 32 + j * 16 + ln;
            const float bv = bias[col];
            #pragma unroll
            for (int r = 0; r < 4; r++)
                C[(size_t)(row0 + r) * E_DIM + col] = acc[i][j][r] + bv;
        }
    }
}

extern "C" void kernel_launch(void* const* d_in, const int* in_sizes, int n_in,
                              void* d_out, int out_size, void* d_ws, size_t ws_size,
                              hipStream_t stream) {
    const float* x         = (const float*)d_in[0];
    const float* in_proj_w = (const float*)d_in[1];
    const float* in_proj_b = (const float*)d_in[2];
    const float* out_w     = (const float*)d_in[3];
    const float* out_b     = (const float*)d_in[4];
    float* out = (float*)d_out;

    const int N = B_SZ * L_SEQ;  // 8192
    const size_t NE = (size_t)N * E_DIM;  // 4.19M elems

    char* p = (char*)d_ws;
    ushort_t* xh  = (ushort_t*)p; p += NE * 2;
    ushort_t* w1h = (ushort_t*)p; p += (size_t)3 * E_DIM * E_DIM * 2;
    ushort_t* w1l = (ushort_t*)p; p += (size_t)3 * E_DIM * E_DIM * 2;
    ushort_t* w2h = (ushort_t*)p; p += (size_t)E_DIM * E_DIM * 2;
    ushort_t* w2l = (ushort_t*)p; p += (size_t)E_DIM * E_DIM * 2;
    ushort_t* qTh = (ushort_t*)p; p += NE * 2;
    ushort_t* qTl = (ushort_t*)p; p += NE * 2;
    ushort_t* kTh = (ushort_t*)p; p += NE * 2;
    ushort_t* kTl = (ushort_t*)p; p += NE * 2;
    ushort_t* vTh = (ushort_t*)p; p += NE * 2;
    ushort_t* ath = (ushort_t*)p; p += NE * 2;
    // total ~63 MB

    convertX<<<2560, 256, 0, stream>>>(x, xh, in_proj_w, w1h, w1l, out_w, w2h, w2l);

    gemm_qkv<<<dim3(64, 12), 256, 0, stream>>>(
        xh, w1h, w1l, in_proj_b, qTh, qTl, kTh, kTl, vTh);

    attn_mfma<<<dim3(L_SEQ / 64, H_DIM, B_SZ), 256, 0, stream>>>(
        qTh, qTl, kTh, kTl, vTh, ath);

    gemm_out<<<dim3(128, 8), 256, 0, stream>>>(
        ath, w2h, w2l, out_b, out);
}

// Round 12
// 156.287 us; speedup vs baseline: 1.2951x; 1.0162x over previous
//
#include <hip/hip_runtime.h>
#include <math.h>

#define E_DIM 512
#define H_DIM 8
#define WIN 128
#define L_SEQ 4096
#define B_SZ 2

typedef unsigned short ushort_t;
typedef unsigned int uint_t;
typedef __attribute__((ext_vector_type(8))) __bf16 bf16x8;
typedef __attribute__((ext_vector_type(4))) float f32x4;

// ---------- bf16 helpers (manual, RNE) ----------
__device__ __forceinline__ ushort_t f2bf(float f) {
    uint_t u = __float_as_uint(f);
    u = u + 0x7fffu + ((u >> 16) & 1u);
    return (ushort_t)(u >> 16);
}
__device__ __forceinline__ float bf2f(ushort_t h) {
    return __uint_as_float((uint_t)h << 16);
}

__device__ __forceinline__ void gload16(const ushort_t* g, ushort_t* l) {
    __builtin_amdgcn_global_load_lds(
        (const __attribute__((address_space(1))) void*)g,
        (__attribute__((address_space(3))) void*)l,
        16, 0, 0);
}

// ===== Tile image (16 rows x 32 k = 512 elems = 1 KB) =====
// idx = slot*8 + (k&7), slot = ((k>>3)&3)*16 + (row&15)  [slot = quad*16+ln]
// A-frag & B-frag both read at lane*8 within a tile image.

// ---------- convert: x -> hi only; w1, w2 -> hi+lo (all tiled) ----------
__global__ __launch_bounds__(256) void convertX(
    const float* __restrict__ x,  ushort_t* __restrict__ xh,
    const float* __restrict__ w1, ushort_t* __restrict__ w1h, ushort_t* __restrict__ w1l,
    const float* __restrict__ w2, ushort_t* __restrict__ w2h, ushort_t* __restrict__ w2l) {
    int sg = blockIdx.x * 256 + threadIdx.x;
    const float* src; ushort_t* dh; ushort_t* dl; bool wantLo;
    if (sg < 524288)      { src = x;  dh = xh;  dl = nullptr; wantLo = false; }
    else if (sg < 622592) { src = w1; dh = w1h; dl = w1l; wantLo = true; sg -= 524288; }
    else                  { src = w2; dh = w2h; dl = w2l; wantLo = true; sg -= 622592; }
    const int tile = sg >> 6, slot = sg & 63;
    const int row = (tile >> 4) * 16 + (slot & 15);
    const int k   = (tile & 15) * 32 + (slot >> 4) * 8;
    const float4 v0 = *(const float4*)&src[(size_t)row * 512 + k];
    const float4 v1 = *(const float4*)&src[(size_t)row * 512 + k + 4];
    const float vv[8] = {v0.x, v0.y, v0.z, v0.w, v1.x, v1.y, v1.z, v1.w};
    union { ushort_t u[8]; ushort4 v[2]; } h, l;
    #pragma unroll
    for (int j = 0; j < 8; j++) {
        const ushort_t a = f2bf(vv[j]);
        h.u[j] = a;
        l.u[j] = f2bf(vv[j] - bf2f(a));
    }
    ((ushort4*)(dh + (size_t)sg * 8))[0] = h.v[0];
    ((ushort4*)(dh + (size_t)sg * 8))[1] = h.v[1];
    if (wantLo) {
        ((ushort4*)(dl + (size_t)sg * 8))[0] = l.v[0];
        ((ushort4*)(dl + (size_t)sg * 8))[1] = l.v[1];
    }
}

// ---------- GEMM1: qkv projection, 2-term (x-hi only), BK=64 ----------
// 128x128 tile, grid (64, 12). by<4: q, [4,8): k, >=8: v.
__global__ __launch_bounds__(256) void gemm_qkv(
    const ushort_t* __restrict__ Ah,
    const ushort_t* __restrict__ Wh, const ushort_t* __restrict__ Wl,
    const float* __restrict__ bias,
    ushort_t* __restrict__ qTh, ushort_t* __restrict__ qTl,
    ushort_t* __restrict__ kTh, ushort_t* __restrict__ kTl,
    ushort_t* __restrict__ vTh) {
    __shared__ __align__(16) ushort_t sAh[16 * 512];
    __shared__ __align__(16) ushort_t sWh[16 * 512];
    __shared__ __align__(16) ushort_t sWl[16 * 512];

    const int tid = threadIdx.x, lane = tid & 63, w = tid >> 6;
    const int wm = w & 1, wn = w >> 1, ln = lane & 15, quad = lane >> 4;
    const int bx = blockIdx.x, by = blockIdx.y;
    const int lo8 = lane * 8;
    const int wu = __builtin_amdgcn_readfirstlane(w);

    f32x4 acc[4][4];
    const f32x4 zero = {0.f, 0.f, 0.f, 0.f};
    #pragma unroll
    for (int i = 0; i < 4; i++)
        #pragma unroll
        for (int j = 0; j < 4; j++) acc[i][j] = zero;

    const ushort_t* pb[12];
    ushort_t* db[12];
    #pragma unroll
    for (int t = 0; t < 12; t++) {
        const int g = wu * 12 + t;
        if (g < 16) {
            pb[t] = Ah + ((size_t)(bx * 8 + (g >> 1)) * 16 + (g & 1)) * 512;
            db[t] = &sAh[g * 512];
        } else if (g < 32) {
            const int u = g - 16;
            pb[t] = Wh + ((size_t)(by * 8 + (u >> 1)) * 16 + (u & 1)) * 512;
            db[t] = &sWh[u * 512];
        } else {
            const int u = g - 32;
            pb[t] = Wl + ((size_t)(by * 8 + (u >> 1)) * 16 + (u & 1)) * 512;
            db[t] = &sWl[u * 512];
        }
    }

    for (int KT = 0; KT < 8; KT++) {
        const int koff = KT * 1024;
        __syncthreads();
        #pragma unroll
        for (int t = 0; t < 12; t++)
            gload16(pb[t] + koff + lo8, db[t]);
        __syncthreads();

        #pragma unroll
        for (int ks = 0; ks < 2; ks++) {
            bf16x8 fah[4];
            #pragma unroll
            for (int i = 0; i < 4; i++)
                fah[i] = *(const bf16x8*)&sAh[((wm * 4 + i) * 2 + ks) * 512 + lo8];
            #pragma unroll
            for (int j = 0; j < 4; j++) {
                const bf16x8 fbh = *(const bf16x8*)&sWh[((wn * 4 + j) * 2 + ks) * 512 + lo8];
                const bf16x8 fbl = *(const bf16x8*)&sWl[((wn * 4 + j) * 2 + ks) * 512 + lo8];
                #pragma unroll
                for (int i = 0; i < 4; i++) {
                    acc[i][j] = __builtin_amdgcn_mfma_f32_16x16x32_bf16(fah[i], fbh, acc[i][j], 0, 0, 0);
                    acc[i][j] = __builtin_amdgcn_mfma_f32_16x16x32_bf16(fah[i], fbl, acc[i][j], 0, 0, 0);
                }
            }
        }
    }

    const int b = bx >> 5;
    const int h = 2 * (by & 3) + wn;
    if (by < 8) {
        ushort_t* dh = (by < 4) ? qTh : kTh;
        ushort_t* dl = (by < 4) ? qTl : kTl;
        #pragma unroll
        for (int i = 0; i < 4; i++) {
            const int rt = (bx & 31) * 8 + wm * 4 + i;
            const size_t tb = ((size_t)(b * 8 + h) * 256 + rt) * 2;
            #pragma unroll
            for (int j = 0; j < 4; j++) {
                const float bv = bias[by * 128 + wn * 64 + j * 16 + ln];
                const size_t tile = tb + (j >> 1);
                #pragma unroll
                for (int r = 0; r < 4; r++) {
                    const int slot = ((j * 2 + (ln >> 3)) & 3) * 16 + quad * 4 + r;
                    const size_t idx = tile * 512 + slot * 8 + (ln & 7);
                    const float v = acc[i][j][r] + bv;
                    const ushort_t hh = f2bf(v);
                    dh[idx] = hh;
                    dl[idx] = f2bf(v - bf2f(hh));
                }
            }
        }
    } else {
        const int kwin = (bx & 31) * 2 + wm;
        #pragma unroll
        for (int i = 0; i < 4; i++) {
            const int kk = i >> 1;
            #pragma unroll
            for (int j = 0; j < 4; j++) {
                const float bv = bias[by * 128 + wn * 64 + j * 16 + ln];
                const size_t tile = (((size_t)(b * 8 + h) * 64 + kwin) * 4 + j) * 2 + kk;
                #pragma unroll
                for (int r = 0; r < 4; r++) {
                    const int klq = quad * 4 + r;
                    const int slot = ((i & 1) * 2 + (klq >> 3)) * 16 + ln;
                    const size_t idx = tile * 512 + slot * 8 + (klq & 7);
                    vTh[idx] = f2bf(acc[i][j][r] + bv);
                }
            }
        }
    }
}

// ---------- attention: 128-query blocks, 8 waves (512 thr), 6 k-iters ----------
// grid (32, 8, 2). Wave w owns q rows [qs+16w, qs+16w+16).
// Staging per iter: waves 0..3 -> K subtiles (hi+lo), waves 4..7 -> V.
__global__ __launch_bounds__(512) void attn_mfma(
    const ushort_t* __restrict__ qTh, const ushort_t* __restrict__ qTl,
    const ushort_t* __restrict__ kTh, const ushort_t* __restrict__ kTl,
    const ushort_t* __restrict__ vTh,
    ushort_t* __restrict__ outh) {
    __shared__ __align__(16) ushort_t sKh[8 * 512];
    __shared__ __align__(16) ushort_t sKl[8 * 512];
    __shared__ __align__(16) ushort_t sV [8 * 512];
    __shared__ __align__(16) ushort_t sP [16 * 512];

    const int qs = blockIdx.x * 128;
    const int h = blockIdx.y, b = blockIdx.z;
    const int bh = b * 8 + h;
    const int tid = threadIdx.x, lane = tid & 63;
    const int w = tid >> 6, ln = lane & 15, quad = lane >> 4;
    const int lo8 = lane * 8;

    // Q fragments
    bf16x8 qf[2][2];
    {
        const size_t qt = ((size_t)bh * 256 + (qs >> 4) + w) * 2;
        qf[0][0] = *(const bf16x8*)(qTh + (qt + 0) * 512 + lo8);
        qf[1][0] = *(const bf16x8*)(qTh + (qt + 1) * 512 + lo8);
        qf[0][1] = *(const bf16x8*)(qTl + (qt + 0) * 512 + lo8);
        qf[1][1] = *(const bf16x8*)(qTl + (qt + 1) * 512 + lo8);
    }

    f32x4 oacc[4];
    const f32x4 zero = {0.f, 0.f, 0.f, 0.f};
    #pragma unroll
    for (int dt = 0; dt < 4; dt++) oacc[dt] = zero;
    float m_run[4], l_run[4];
    #pragma unroll
    for (int r = 0; r < 4; r++) { m_run[r] = -1e30f; l_run[r] = 0.f; }

    const float cscale = 0.125f * 1.44269504f;
    const int qlo = qs + 16 * w;  // this wave's q-subtile base

    for (int kt = 0; kt < 6; kt++) {
        const int ks = qs - 128 + kt * 64;

        __syncthreads();  // prev iter's reads of sK/sV/sP done

        if (w < 4) {
            int st = (qs >> 4) - 8 + kt * 4 + w;
            st = st < 0 ? 0 : (st > 255 ? 255 : st);
            const size_t kb = ((size_t)bh * 256 + st) * 2 * 512 + lo8;
            gload16(kTh + kb,       &sKh[(w * 2 + 0) * 512]);
            gload16(kTh + kb + 512, &sKh[(w * 2 + 1) * 512]);
            gload16(kTl + kb,       &sKl[(w * 2 + 0) * 512]);
            gload16(kTl + kb + 512, &sKl[(w * 2 + 1) * 512]);
        } else {
            const int u = w - 4;
            int vw = (qs >> 6) - 2 + kt;
            vw = vw < 0 ? 0 : (vw > 63 ? 63 : vw);
            const size_t vb = (((size_t)bh * 64 + vw) * 4 + u) * 2 * 512 + lo8;
            gload16(vTh + vb,       &sV[(u * 2 + 0) * 512]);
            gload16(vTh + vb + 512, &sV[(u * 2 + 1) * 512]);
        }
        __syncthreads();  // staging visible

        // S = Q K^T (hh + hl + lh)
        f32x4 sacc[4];
        #pragma unroll
        for (int jt = 0; jt < 4; jt++) {
            f32x4 a = zero;
            const int klo = ks + 16 * jt;
            const bool dead = (klo > qlo + 15 + WIN) || (klo + 15 < qlo - WIN) ||
                              (klo >= L_SEQ) || (klo + 15 < 0);
            if (!dead) {
                #pragma unroll
                for (int kk = 0; kk < 2; kk++) {
                    const bf16x8 kh = *(const bf16x8*)&sKh[(jt * 2 + kk) * 512 + lo8];
                    const bf16x8 klo2 = *(const bf16x8*)&sKl[(jt * 2 + kk) * 512 + lo8];
                    a = __builtin_amdgcn_mfma_f32_16x16x32_bf16(qf[kk][0], kh, a, 0, 0, 0);
                    a = __builtin_amdgcn_mfma_f32_16x16x32_bf16(qf[kk][0], klo2, a, 0, 0, 0);
                    a = __builtin_amdgcn_mfma_f32_16x16x32_bf16(qf[kk][1], kh, a, 0, 0, 0);
                }
            }
            sacc[jt] = a;
        }

        // mask + online softmax
        float u[4][4];
        #pragma unroll
        for (int jt = 0; jt < 4; jt++) {
            const int kcol = ks + 16 * jt + ln;
            #pragma unroll
            for (int r = 0; r < 4; r++) {
                const int qrow = qlo + quad * 4 + r;
                const int dist = qrow > kcol ? qrow - kcol : kcol - qrow;
                const bool ok = (kcol >= 0) && (kcol < L_SEQ) && (dist >= 1) && (dist <= WIN);
                u[jt][r] = ok ? sacc[jt][r] * cscale : -INFINITY;
            }
        }
        float mk[4];
        #pragma unroll
        for (int r = 0; r < 4; r++)
            mk[r] = fmaxf(fmaxf(u[0][r], u[1][r]), fmaxf(u[2][r], u[3][r]));
        #pragma unroll
        for (int off = 1; off <= 8; off <<= 1)
            #pragma unroll
            for (int r = 0; r < 4; r++)
                mk[r] = fmaxf(mk[r], __shfl_xor(mk[r], off));

        float alpha[4], psum[4], p[4][4];
        #pragma unroll
        for (int r = 0; r < 4; r++) {
            const float mnew = fmaxf(fmaxf(m_run[r], mk[r]), -1e30f);
            alpha[r] = exp2f(m_run[r] - mnew);
            m_run[r] = mnew;
            psum[r] = 0.f;
            #pragma unroll
            for (int jt = 0; jt < 4; jt++) {
                p[jt][r] = exp2f(u[jt][r] - mnew);
                psum[r] += p[jt][r];
            }
        }
        #pragma unroll
        for (int off = 1; off <= 8; off <<= 1)
            #pragma unroll
            for (int r = 0; r < 4; r++)
                psum[r] += __shfl_xor(psum[r], off);
        #pragma unroll
        for (int r = 0; r < 4; r++)
            l_run[r] = l_run[r] * alpha[r] + psum[r];

        #pragma unroll
        for (int dt = 0; dt < 4; dt++)
            #pragma unroll
            for (int r = 0; r < 4; r++)
                oacc[dt][r] *= alpha[r];

        // P (hi only) -> own wave's A-frag tile images
        #pragma unroll
        for (int jt = 0; jt < 4; jt++)
            #pragma unroll
            for (int r = 0; r < 4; r++) {
                const int slot = ((jt & 1) * 2 + (ln >> 3)) * 16 + quad * 4 + r;
                sP[w * 1024 + (jt >> 1) * 512 + slot * 8 + (ln & 7)] = f2bf(p[jt][r]);
            }

        // O += P V (hi x hi)
        #pragma unroll
        for (int kk = 0; kk < 2; kk++) {
            const bf16x8 pf = *(const bf16x8*)&sP[w * 1024 + kk * 512 + lo8];
            #pragma unroll
            for (int dt = 0; dt < 4; dt++) {
                const bf16x8 vf = *(const bf16x8*)&sV[(dt * 2 + kk) * 512 + lo8];
                oacc[dt] = __builtin_amdgcn_mfma_f32_16x16x32_bf16(pf, vf, oacc[dt], 0, 0, 0);
            }
        }
    }

    // epilogue: write hi bf16 in GEMM2's A-frag tiled layout
    const int Rt = ((b * L_SEQ + qs) >> 4) + w;
    #pragma unroll
    for (int r = 0; r < 4; r++) {
        const float inv_l = 1.f / l_run[r];
        #pragma unroll
        for (int dt = 0; dt < 4; dt++) {
            const float v = oacc[dt][r] * inv_l;
            const int tile = Rt * 16 + h * 2 + (dt >> 1);
            const int slot = ((dt & 1) * 2 + (ln >> 3)) * 16 + quad * 4 + r;
            const size_t idx = (size_t)tile * 512 + slot * 8 + (ln & 7);
            outh[idx] = f2bf(v);
        }
    }
}

// ---------- GEMM2: out projection, 128x64 tile, 8 waves, BK=64, grid (64,8) --
__global__ __launch_bounds__(512) void gemm_out(
    const ushort_t* __restrict__ Ah,
    const ushort_t* __restrict__ Wh, const ushort_t* __restrict__ Wl,
    const float* __restrict__ bias, float* __restrict__ C) {
    __shared__ __align__(16) ushort_t sAh[16 * 512];
    __shared__ __align__(16) ushort_t sWh[8 * 512];
    __shared__ __align__(16) ushort_t sWl[8 * 512];

    const int tid = threadIdx.x, lane = tid & 63, w = tid >> 6;
    const int wm = w & 3, wn = w >> 2, ln = lane & 15, quad = lane >> 4;
    const int bx = blockIdx.x, by = blockIdx.y;
    const int lo8 = lane * 8;
    const int wu = __builtin_amdgcn_readfirstlane(w);

    f32x4 acc[2][2];
    const f32x4 zero = {0.f, 0.f, 0.f, 0.f};
    #pragma unroll
    for (int i = 0; i < 2; i++)
        #pragma unroll
        for (int j = 0; j < 2; j++) acc[i][j] = zero;

    // staging: 32 images (A 16, Wh 8, Wl 8), 4 per wave
    const ushort_t* pb[4];
    ushort_t* db[4];
    #pragma unroll
    for (int t = 0; t < 4; t++) {
        const int g = wu * 4 + t;
        if (g < 16) {
            pb[t] = Ah + ((size_t)(bx * 8 + (g >> 1)) * 16 + (g & 1)) * 512;
            db[t] = &sAh[g * 512];
        } else if (g < 24) {
            const int u = g - 16;
            pb[t] = Wh + ((size_t)(by * 4 + (u >> 1)) * 16 + (u & 1)) * 512;
            db[t] = &sWh[u * 512];
        } else {
            const int u = g - 24;
            pb[t] = Wl + ((size_t)(by * 4 + (u >> 1)) * 16 + (u & 1)) * 512;
            db[t] = &sWl[u * 512];
        }
    }

    for (int KT = 0; KT < 8; KT++) {
        const int koff = KT * 1024;
        __syncthreads();
        #pragma unroll
        for (int t = 0; t < 4; t++)
            gload16(pb[t] + koff + lo8, db[t]);
        __syncthreads();

        #pragma unroll
        for (int ks = 0; ks < 2; ks++) {
            bf16x8 fah[2];
            #pragma unroll
            for (int i = 0; i < 2; i++)
                fah[i] = *(const bf16x8*)&sAh[((wm * 2 + i) * 2 + ks) * 512 + lo8];
            #pragma unroll
            for (int j = 0; j < 2; j++) {
                const bf16x8 fbh = *(const bf16x8*)&sWh[((wn * 2 + j) * 2 + ks) * 512 + lo8];
                const bf16x8 fbl = *(const bf16x8*)&sWl[((wn * 2 + j) * 2 + ks) * 512 + lo8];
                #pragma unroll
                for (int i = 0; i < 2; i++) {
                    acc[i][j] = __builtin_amdgcn_mfma_f32_16x16x32_bf16(fah[i], fbh, acc[i][j], 0, 0, 0);
                    acc[i][j] = __builtin_amdgcn_mfma_f32_16x16x32_bf16(fah[i], fbl, acc[i][j], 0, 0, 0);
                }
            }
        }
    }

    #pragma unroll
    for (int i = 0; i < 2; i++) {
        const int row0 = bx * 128 + wm * 32 + i * 16 + quad * 4;
        #pragma unroll
        for (int j = 0; j < 2; j++) {
            const int col = by * 64 + wn * 32 + j * 16 + ln;
            const float bv = bias[col];
            #pragma unroll
            for (int r = 0; r < 4; r++)
                C[(size_t)(row0 + r) * E_DIM + col] = acc[i][j][r] + bv;
        }
    }
}

extern "C" void kernel_launch(void* const* d_in, const int* in_sizes, int n_in,
                              void* d_out, int out_size, void* d_ws, size_t ws_size,
                              hipStream_t stream) {
    const float* x         = (const float*)d_in[0];
    const float* in_proj_w = (const float*)d_in[1];
    const float* in_proj_b = (const float*)d_in[2];
    const float* out_w     = (const float*)d_in[3];
    const float* out_b     = (const float*)d_in[4];
    float* out = (float*)d_out;

    const int N = B_SZ * L_SEQ;  // 8192
    const size_t NE = (size_t)N * E_DIM;  // 4.19M elems

    char* p = (char*)d_ws;
    ushort_t* xh  = (ushort_t*)p; p += NE * 2;
    ushort_t* w1h = (ushort_t*)p; p += (size_t)3 * E_DIM * E_DIM * 2;
    ushort_t* w1l = (ushort_t*)p; p += (size_t)3 * E_DIM * E_DIM * 2;
    ushort_t* w2h = (ushort_t*)p; p += (size_t)E_DIM * E_DIM * 2;
    ushort_t* w2l = (ushort_t*)p; p += (size_t)E_DIM * E_DIM * 2;
    ushort_t* qTh = (ushort_t*)p; p += NE * 2;
    ushort_t* qTl = (ushort_t*)p; p += NE * 2;
    ushort_t* kTh = (ushort_t*)p; p += NE * 2;
    ushort_t* kTl = (ushort_t*)p; p += NE * 2;
    ushort_t* vTh = (ushort_t*)p; p += NE * 2;
    ushort_t* ath = (ushort_t*)p; p += NE * 2;
    // total ~63 MB

    convertX<<<2560, 256, 0, stream>>>(x, xh, in_proj_w, w1h, w1l, out_w, w2h, w2l);

    gemm_qkv<<<dim3(64, 12), 256, 0, stream>>>(
        xh, w1h, w1l, in_proj_b, qTh, qTl, kTh, kTl, vTh);

    attn_mfma<<<dim3(L_SEQ / 128, H_DIM, B_SZ), 512, 0, stream>>>(
        qTh, qTl, kTh, kTl, vTh, ath);

    gemm_out<<<dim3(64, 8), 512, 0, stream>>>(
        ath, w2h, w2l, out_b, out);
}

// Round 13
// 152.849 us; speedup vs baseline: 1.3242x; 1.0225x over previous
//
#include <hip/hip_runtime.h>
#include <math.h>

#define E_DIM 512
#define H_DIM 8
#define WIN 128
#define L_SEQ 4096
#define B_SZ 2

typedef unsigned short ushort_t;
typedef unsigned int uint_t;
typedef __attribute__((ext_vector_type(8))) __bf16 bf16x8;
typedef __attribute__((ext_vector_type(4))) float f32x4;

// ---------- bf16 helpers (manual, RNE) ----------
__device__ __forceinline__ ushort_t f2bf(float f) {
    uint_t u = __float_as_uint(f);
    u = u + 0x7fffu + ((u >> 16) & 1u);
    return (ushort_t)(u >> 16);
}
__device__ __forceinline__ float bf2f(ushort_t h) {
    return __uint_as_float((uint_t)h << 16);
}

__device__ __forceinline__ void gload16(const ushort_t* g, ushort_t* l) {
    __builtin_amdgcn_global_load_lds(
        (const __attribute__((address_space(1))) void*)g,
        (__attribute__((address_space(3))) void*)l,
        16, 0, 0);
}

// ===== Tile image (16 rows x 32 k = 512 elems = 1 KB) =====
// idx = slot*8 + (k&7), slot = ((k>>3)&3)*16 + (row&15)  [slot = quad*16+ln]
// A-frag & B-frag both read at lane*8 within a tile image.

// ---------- convert: x -> hi only; w1, w2 -> hi+lo (all tiled) ----------
__global__ __launch_bounds__(256) void convertX(
    const float* __restrict__ x,  ushort_t* __restrict__ xh,
    const float* __restrict__ w1, ushort_t* __restrict__ w1h, ushort_t* __restrict__ w1l,
    const float* __restrict__ w2, ushort_t* __restrict__ w2h, ushort_t* __restrict__ w2l) {
    int sg = blockIdx.x * 256 + threadIdx.x;
    const float* src; ushort_t* dh; ushort_t* dl; bool wantLo;
    if (sg < 524288)      { src = x;  dh = xh;  dl = nullptr; wantLo = false; }
    else if (sg < 622592) { src = w1; dh = w1h; dl = w1l; wantLo = true; sg -= 524288; }
    else                  { src = w2; dh = w2h; dl = w2l; wantLo = true; sg -= 622592; }
    const int tile = sg >> 6, slot = sg & 63;
    const int row = (tile >> 4) * 16 + (slot & 15);
    const int k   = (tile & 15) * 32 + (slot >> 4) * 8;
    const float4 v0 = *(const float4*)&src[(size_t)row * 512 + k];
    const float4 v1 = *(const float4*)&src[(size_t)row * 512 + k + 4];
    const float vv[8] = {v0.x, v0.y, v0.z, v0.w, v1.x, v1.y, v1.z, v1.w};
    union { ushort_t u[8]; ushort4 v[2]; } h, l;
    #pragma unroll
    for (int j = 0; j < 8; j++) {
        const ushort_t a = f2bf(vv[j]);
        h.u[j] = a;
        l.u[j] = f2bf(vv[j] - bf2f(a));
    }
    ((ushort4*)(dh + (size_t)sg * 8))[0] = h.v[0];
    ((ushort4*)(dh + (size_t)sg * 8))[1] = h.v[1];
    if (wantLo) {
        ((ushort4*)(dl + (size_t)sg * 8))[0] = l.v[0];
        ((ushort4*)(dl + (size_t)sg * 8))[1] = l.v[1];
    }
}

// ---------- GEMM1: qkv projection, 2-term (x-hi only), BK=32, 2-deep dbuf ----
// 128x128 tile, grid (64, 12). by<4: q, [4,8): k, >=8: v.
// Pipeline: stage(0); loop{ barrier; prefetch(kt+1 -> other buf); compute(kt); }
__global__ __launch_bounds__(256) void gemm_qkv(
    const ushort_t* __restrict__ Ah,
    const ushort_t* __restrict__ Wh, const ushort_t* __restrict__ Wl,
    const float* __restrict__ bias,
    ushort_t* __restrict__ qTh, ushort_t* __restrict__ qTl,
    ushort_t* __restrict__ kTh, ushort_t* __restrict__ kTl,
    ushort_t* __restrict__ vTh) {
    __shared__ __align__(16) ushort_t sAh[2][8 * 512];
    __shared__ __align__(16) ushort_t sWh[2][8 * 512];
    __shared__ __align__(16) ushort_t sWl[2][8 * 512];

    const int tid = threadIdx.x, lane = tid & 63, w = tid >> 6;
    const int wm = w & 1, wn = w >> 1, ln = lane & 15, quad = lane >> 4;
    const int bx = blockIdx.x, by = blockIdx.y;
    const int lo8 = lane * 8;
    const int wu = __builtin_amdgcn_readfirstlane(w);

    f32x4 acc[4][4];
    const f32x4 zero = {0.f, 0.f, 0.f, 0.f};
    #pragma unroll
    for (int i = 0; i < 4; i++)
        #pragma unroll
        for (int j = 0; j < 4; j++) acc[i][j] = zero;

    // staging: 24 images per k-group (A 8, Wh 8, Wl 8), 6 per wave
    const ushort_t* pb[6];
    ushort_t* db0[6];
    ushort_t* db1[6];
    #pragma unroll
    for (int t = 0; t < 6; t++) {
        const int g = wu * 6 + t;
        if (g < 8) {
            pb[t] = Ah + ((size_t)(bx * 8 + g) * 16) * 512;
            db0[t] = &sAh[0][g * 512]; db1[t] = &sAh[1][g * 512];
        } else if (g < 16) {
            const int u = g - 8;
            pb[t] = Wh + ((size_t)(by * 8 + u) * 16) * 512;
            db0[t] = &sWh[0][u * 512]; db1[t] = &sWh[1][u * 512];
        } else {
            const int u = g - 16;
            pb[t] = Wl + ((size_t)(by * 8 + u) * 16) * 512;
            db0[t] = &sWl[0][u * 512]; db1[t] = &sWl[1][u * 512];
        }
    }

    // prologue: stage k-group 0 into buf 0
    #pragma unroll
    for (int t = 0; t < 6; t++)
        gload16(pb[t] + lo8, db0[t]);

    for (int kt = 0; kt < 16; kt++) {
        __syncthreads();  // drains stage(kt); all waves done reading buf[(kt+1)&1]
        if (kt < 15) {
            const int koff = (kt + 1) * 512;
            if ((kt + 1) & 1) {
                #pragma unroll
                for (int t = 0; t < 6; t++) gload16(pb[t] + koff + lo8, db1[t]);
            } else {
                #pragma unroll
                for (int t = 0; t < 6; t++) gload16(pb[t] + koff + lo8, db0[t]);
            }
        }
        const int cb = kt & 1;
        bf16x8 fah[4];
        #pragma unroll
        for (int i = 0; i < 4; i++)
            fah[i] = *(const bf16x8*)&sAh[cb][(wm * 4 + i) * 512 + lo8];
        #pragma unroll
        for (int j = 0; j < 4; j++) {
            const bf16x8 fbh = *(const bf16x8*)&sWh[cb][(wn * 4 + j) * 512 + lo8];
            const bf16x8 fbl = *(const bf16x8*)&sWl[cb][(wn * 4 + j) * 512 + lo8];
            #pragma unroll
            for (int i = 0; i < 4; i++) {
                acc[i][j] = __builtin_amdgcn_mfma_f32_16x16x32_bf16(fah[i], fbh, acc[i][j], 0, 0, 0);
                acc[i][j] = __builtin_amdgcn_mfma_f32_16x16x32_bf16(fah[i], fbl, acc[i][j], 0, 0, 0);
            }
        }
    }

    // ---- epilogue: C/D layout col=ln (within j-tile), row=quad*4+r ----
    const int b = bx >> 5;
    const int h = 2 * (by & 3) + wn;
    if (by < 8) {
        ushort_t* dh = (by < 4) ? qTh : kTh;
        ushort_t* dl = (by < 4) ? qTl : kTl;
        #pragma unroll
        for (int i = 0; i < 4; i++) {
            const int rt = (bx & 31) * 8 + wm * 4 + i;
            const size_t tb = ((size_t)(b * 8 + h) * 256 + rt) * 2;
            #pragma unroll
            for (int j = 0; j < 4; j++) {
                const float bv = bias[by * 128 + wn * 64 + j * 16 + ln];
                const size_t tile = tb + (j >> 1);
                #pragma unroll
                for (int r = 0; r < 4; r++) {
                    const int slot = ((j * 2 + (ln >> 3)) & 3) * 16 + quad * 4 + r;
                    const size_t idx = tile * 512 + slot * 8 + (ln & 7);
                    const float v = acc[i][j][r] + bv;
                    const ushort_t hh = f2bf(v);
                    dh[idx] = hh;
                    dl[idx] = f2bf(v - bf2f(hh));
                }
            }
        }
    } else {
        const int kwin = (bx & 31) * 2 + wm;
        #pragma unroll
        for (int i = 0; i < 4; i++) {
            const int kk = i >> 1;
            #pragma unroll
            for (int j = 0; j < 4; j++) {
                const float bv = bias[by * 128 + wn * 64 + j * 16 + ln];
                const size_t tile = (((size_t)(b * 8 + h) * 64 + kwin) * 4 + j) * 2 + kk;
                #pragma unroll
                for (int r = 0; r < 4; r++) {
                    const int klq = quad * 4 + r;
                    const int slot = ((i & 1) * 2 + (klq >> 3)) * 16 + ln;
                    const size_t idx = tile * 512 + slot * 8 + (klq & 7);
                    vTh[idx] = f2bf(acc[i][j][r] + bv);
                }
            }
        }
    }
}

// ---------- attention: 128-query blocks, 8 waves (512 thr), 6 k-iters ----------
__global__ __launch_bounds__(512) void attn_mfma(
    const ushort_t* __restrict__ qTh, const ushort_t* __restrict__ qTl,
    const ushort_t* __restrict__ kTh, const ushort_t* __restrict__ kTl,
    const ushort_t* __restrict__ vTh,
    ushort_t* __restrict__ outh) {
    __shared__ __align__(16) ushort_t sKh[8 * 512];
    __shared__ __align__(16) ushort_t sKl[8 * 512];
    __shared__ __align__(16) ushort_t sV [8 * 512];
    __shared__ __align__(16) ushort_t sP [16 * 512];

    const int qs = blockIdx.x * 128;
    const int h = blockIdx.y, b = blockIdx.z;
    const int bh = b * 8 + h;
    const int tid = threadIdx.x, lane = tid & 63;
    const int w = tid >> 6, ln = lane & 15, quad = lane >> 4;
    const int lo8 = lane * 8;

    bf16x8 qf[2][2];
    {
        const size_t qt = ((size_t)bh * 256 + (qs >> 4) + w) * 2;
        qf[0][0] = *(const bf16x8*)(qTh + (qt + 0) * 512 + lo8);
        qf[1][0] = *(const bf16x8*)(qTh + (qt + 1) * 512 + lo8);
        qf[0][1] = *(const bf16x8*)(qTl + (qt + 0) * 512 + lo8);
        qf[1][1] = *(const bf16x8*)(qTl + (qt + 1) * 512 + lo8);
    }

    f32x4 oacc[4];
    const f32x4 zero = {0.f, 0.f, 0.f, 0.f};
    #pragma unroll
    for (int dt = 0; dt < 4; dt++) oacc[dt] = zero;
    float m_run[4], l_run[4];
    #pragma unroll
    for (int r = 0; r < 4; r++) { m_run[r] = -1e30f; l_run[r] = 0.f; }

    const float cscale = 0.125f * 1.44269504f;
    const int qlo = qs + 16 * w;

    for (int kt = 0; kt < 6; kt++) {
        const int ks = qs - 128 + kt * 64;

        __syncthreads();

        if (w < 4) {
            int st = (qs >> 4) - 8 + kt * 4 + w;
            st = st < 0 ? 0 : (st > 255 ? 255 : st);
            const size_t kb = ((size_t)bh * 256 + st) * 2 * 512 + lo8;
            gload16(kTh + kb,       &sKh[(w * 2 + 0) * 512]);
            gload16(kTh + kb + 512, &sKh[(w * 2 + 1) * 512]);
            gload16(kTl + kb,       &sKl[(w * 2 + 0) * 512]);
            gload16(kTl + kb + 512, &sKl[(w * 2 + 1) * 512]);
        } else {
            const int u = w - 4;
            int vw = (qs >> 6) - 2 + kt;
            vw = vw < 0 ? 0 : (vw > 63 ? 63 : vw);
            const size_t vb = (((size_t)bh * 64 + vw) * 4 + u) * 2 * 512 + lo8;
            gload16(vTh + vb,       &sV[(u * 2 + 0) * 512]);
            gload16(vTh + vb + 512, &sV[(u * 2 + 1) * 512]);
        }
        __syncthreads();

        f32x4 sacc[4];
        #pragma unroll
        for (int jt = 0; jt < 4; jt++) {
            f32x4 a = zero;
            const int klo = ks + 16 * jt;
            const bool dead = (klo > qlo + 15 + WIN) || (klo + 15 < qlo - WIN) ||
                              (klo >= L_SEQ) || (klo + 15 < 0);
            if (!dead) {
                #pragma unroll
                for (int kk = 0; kk < 2; kk++) {
                    const bf16x8 kh = *(const bf16x8*)&sKh[(jt * 2 + kk) * 512 + lo8];
                    const bf16x8 klo2 = *(const bf16x8*)&sKl[(jt * 2 + kk) * 512 + lo8];
                    a = __builtin_amdgcn_mfma_f32_16x16x32_bf16(qf[kk][0], kh, a, 0, 0, 0);
                    a = __builtin_amdgcn_mfma_f32_16x16x32_bf16(qf[kk][0], klo2, a, 0, 0, 0);
                    a = __builtin_amdgcn_mfma_f32_16x16x32_bf16(qf[kk][1], kh, a, 0, 0, 0);
                }
            }
            sacc[jt] = a;
        }

        float u[4][4];
        #pragma unroll
        for (int jt = 0; jt < 4; jt++) {
            const int kcol = ks + 16 * jt + ln;
            #pragma unroll
            for (int r = 0; r < 4; r++) {
                const int qrow = qlo + quad * 4 + r;
                const int dist = qrow > kcol ? qrow - kcol : kcol - qrow;
                const bool ok = (kcol >= 0) && (kcol < L_SEQ) && (dist >= 1) && (dist <= WIN);
                u[jt][r] = ok ? sacc[jt][r] * cscale : -INFINITY;
            }
        }
        float mk[4];
        #pragma unroll
        for (int r = 0; r < 4; r++)
            mk[r] = fmaxf(fmaxf(u[0][r], u[1][r]), fmaxf(u[2][r], u[3][r]));
        #pragma unroll
        for (int off = 1; off <= 8; off <<= 1)
            #pragma unroll
            for (int r = 0; r < 4; r++)
                mk[r] = fmaxf(mk[r], __shfl_xor(mk[r], off));

        float alpha[4], psum[4], p[4][4];
        #pragma unroll
        for (int r = 0; r < 4; r++) {
            const float mnew = fmaxf(fmaxf(m_run[r], mk[r]), -1e30f);
            alpha[r] = exp2f(m_run[r] - mnew);
            m_run[r] = mnew;
            psum[r] = 0.f;
            #pragma unroll
            for (int jt = 0; jt < 4; jt++) {
                p[jt][r] = exp2f(u[jt][r] - mnew);
                psum[r] += p[jt][r];
            }
        }
        #pragma unroll
        for (int off = 1; off <= 8; off <<= 1)
            #pragma unroll
            for (int r = 0; r < 4; r++)
                psum[r] += __shfl_xor(psum[r], off);
        #pragma unroll
        for (int r = 0; r < 4; r++)
            l_run[r] = l_run[r] * alpha[r] + psum[r];

        #pragma unroll
        for (int dt = 0; dt < 4; dt++)
            #pragma unroll
            for (int r = 0; r < 4; r++)
                oacc[dt][r] *= alpha[r];

        #pragma unroll
        for (int jt = 0; jt < 4; jt++)
            #pragma unroll
            for (int r = 0; r < 4; r++) {
                const int slot = ((jt & 1) * 2 + (ln >> 3)) * 16 + quad * 4 + r;
                sP[w * 1024 + (jt >> 1) * 512 + slot * 8 + (ln & 7)] = f2bf(p[jt][r]);
            }

        #pragma unroll
        for (int kk = 0; kk < 2; kk++) {
            const bf16x8 pf = *(const bf16x8*)&sP[w * 1024 + kk * 512 + lo8];
            #pragma unroll
            for (int dt = 0; dt < 4; dt++) {
                const bf16x8 vf = *(const bf16x8*)&sV[(dt * 2 + kk) * 512 + lo8];
                oacc[dt] = __builtin_amdgcn_mfma_f32_16x16x32_bf16(pf, vf, oacc[dt], 0, 0, 0);
            }
        }
    }

    const int Rt = ((b * L_SEQ + qs) >> 4) + w;
    #pragma unroll
    for (int r = 0; r < 4; r++) {
        const float inv_l = 1.f / l_run[r];
        #pragma unroll
        for (int dt = 0; dt < 4; dt++) {
            const float v = oacc[dt][r] * inv_l;
            const int tile = Rt * 16 + h * 2 + (dt >> 1);
            const int slot = ((dt & 1) * 2 + (ln >> 3)) * 16 + quad * 4 + r;
            const size_t idx = (size_t)tile * 512 + slot * 8 + (ln & 7);
            outh[idx] = f2bf(v);
        }
    }
}

// ---------- GEMM2: out projection, 128x64, 8 waves, BK=64, 2-deep dbuf ------
__global__ __launch_bounds__(512) void gemm_out(
    const ushort_t* __restrict__ Ah,
    const ushort_t* __restrict__ Wh, const ushort_t* __restrict__ Wl,
    const float* __restrict__ bias, float* __restrict__ C) {
    __shared__ __align__(16) ushort_t sAh[2][16 * 512];
    __shared__ __align__(16) ushort_t sWh[2][8 * 512];
    __shared__ __align__(16) ushort_t sWl[2][8 * 512];

    const int tid = threadIdx.x, lane = tid & 63, w = tid >> 6;
    const int wm = w & 3, wn = w >> 2, ln = lane & 15, quad = lane >> 4;
    const int bx = blockIdx.x, by = blockIdx.y;
    const int lo8 = lane * 8;
    const int wu = __builtin_amdgcn_readfirstlane(w);

    f32x4 acc[2][2];
    const f32x4 zero = {0.f, 0.f, 0.f, 0.f};
    #pragma unroll
    for (int i = 0; i < 2; i++)
        #pragma unroll
        for (int j = 0; j < 2; j++) acc[i][j] = zero;

    // staging: 32 images per KT (A 16, Wh 8, Wl 8), 4 per wave
    const ushort_t* pb[4];
    ushort_t* db0[4];
    ushort_t* db1[4];
    #pragma unroll
    for (int t = 0; t < 4; t++) {
        const int g = wu * 4 + t;
        if (g < 16) {
            pb[t] = Ah + ((size_t)(bx * 8 + (g >> 1)) * 16 + (g & 1)) * 512;
            db0[t] = &sAh[0][g * 512]; db1[t] = &sAh[1][g * 512];
        } else if (g < 24) {
            const int u = g - 16;
            pb[t] = Wh + ((size_t)(by * 4 + (u >> 1)) * 16 + (u & 1)) * 512;
            db0[t] = &sWh[0][u * 512]; db1[t] = &sWh[1][u * 512];
        } else {
            const int u = g - 24;
            pb[t] = Wl + ((size_t)(by * 4 + (u >> 1)) * 16 + (u & 1)) * 512;
            db0[t] = &sWl[0][u * 512]; db1[t] = &sWl[1][u * 512];
        }
    }

    // prologue: KT=0 into buf 0
    #pragma unroll
    for (int t = 0; t < 4; t++)
        gload16(pb[t] + lo8, db0[t]);

    for (int KT = 0; KT < 8; KT++) {
        __syncthreads();
        if (KT < 7) {
            const int koff = (KT + 1) * 1024;
            if ((KT + 1) & 1) {
                #pragma unroll
                for (int t = 0; t < 4; t++) gload16(pb[t] + koff + lo8, db1[t]);
            } else {
                #pragma unroll
                for (int t = 0; t < 4; t++) gload16(pb[t] + koff + lo8, db0[t]);
            }
        }
        const int cb = KT & 1;
        #pragma unroll
        for (int ks = 0; ks < 2; ks++) {
            bf16x8 fah[2];
            #pragma unroll
            for (int i = 0; i < 2; i++)
                fah[i] = *(const bf16x8*)&sAh[cb][((wm * 2 + i) * 2 + ks) * 512 + lo8];
            #pragma unroll
            for (int j = 0; j < 2; j++) {
                const bf16x8 fbh = *(const bf16x8*)&sWh[cb][((wn * 2 + j) * 2 + ks) * 512 + lo8];
                const bf16x8 fbl = *(const bf16x8*)&sWl[cb][((wn * 2 + j) * 2 + ks) * 512 + lo8];
                #pragma unroll
                for (int i = 0; i < 2; i++) {
                    acc[i][j] = __builtin_amdgcn_mfma_f32_16x16x32_bf16(fah[i], fbh, acc[i][j], 0, 0, 0);
                    acc[i][j] = __builtin_amdgcn_mfma_f32_16x16x32_bf16(fah[i], fbl, acc[i][j], 0, 0, 0);
                }
            }
        }
    }

    #pragma unroll
    for (int i = 0; i < 2; i++) {
        const int row0 = bx * 128 + wm * 32 + i * 16 + quad * 4;
        #pragma unroll
        for (int j = 0; j < 2; j++) {
            const int col = by * 64 + wn * 32 + j * 16 + ln;
            const float bv = bias[col];
            #pragma unroll
            for (int r = 0; r < 4; r++)
                C[(size_t)(row0 + r) * E_DIM + col] = acc[i][j][r] + bv;
        }
    }
}

extern "C" void kernel_launch(void* const* d_in, const int* in_sizes, int n_in,
                              void* d_out, int out_size, void* d_ws, size_t ws_size,
                              hipStream_t stream) {
    const float* x         = (const float*)d_in[0];
    const float* in_proj_w = (const float*)d_in[1];
    const float* in_proj_b = (const float*)d_in[2];
    const float* out_w     = (const float*)d_in[3];
    const float* out_b     = (const float*)d_in[4];
    float* out = (float*)d_out;

    const int N = B_SZ * L_SEQ;  // 8192
    const size_t NE = (size_t)N * E_DIM;  // 4.19M elems

    char* p = (char*)d_ws;
    ushort_t* xh  = (ushort_t*)p; p += NE * 2;
    ushort_t* w1h = (ushort_t*)p; p += (size_t)3 * E_DIM * E_DIM * 2;
    ushort_t* w1l = (ushort_t*)p; p += (size_t)3 * E_DIM * E_DIM * 2;
    ushort_t* w2h = (ushort_t*)p; p += (size_t)E_DIM * E_DIM * 2;
    ushort_t* w2l = (ushort_t*)p; p += (size_t)E_DIM * E_DIM * 2;
    ushort_t* qTh = (ushort_t*)p; p += NE * 2;
    ushort_t* qTl = (ushort_t*)p; p += NE * 2;
    ushort_t* kTh = (ushort_t*)p; p += NE * 2;
    ushort_t* kTl = (ushort_t*)p; p += NE * 2;
    ushort_t* vTh = (ushort_t*)p; p += NE * 2;
    ushort_t* ath = (ushort_t*)p; p += NE * 2;
    // total ~63 MB

    convertX<<<2560, 256, 0, stream>>>(x, xh, in_proj_w, w1h, w1l, out_w, w2h, w2l);

    gemm_qkv<<<dim3(64, 12), 256, 0, stream>>>(
        xh, w1h, w1l, in_proj_b, qTh, qTl, kTh, kTl, vTh);

    attn_mfma<<<dim3(L_SEQ / 128, H_DIM, B_SZ), 512, 0, stream>>>(
        qTh, qTl, kTh, kTl, vTh, ath);

    gemm_out<<<dim3(64, 8), 512, 0, stream>>>(
        ath, w2h, w2l, out_b, out);
}

// Round 14
// 144.303 us; speedup vs baseline: 1.4027x; 1.0592x over previous
//
#include <hip/hip_runtime.h>
#include <math.h>

#define E_DIM 512
#define H_DIM 8
#define WIN 128
#define L_SEQ 4096
#define B_SZ 2

typedef unsigned short ushort_t;
typedef unsigned int uint_t;
typedef __attribute__((ext_vector_type(8))) __bf16 bf16x8;
typedef __attribute__((ext_vector_type(4))) float f32x4;

// ---------- bf16 helpers (manual, RNE) ----------
__device__ __forceinline__ ushort_t f2bf(float f) {
    uint_t u = __float_as_uint(f);
    u = u + 0x7fffu + ((u >> 16) & 1u);
    return (ushort_t)(u >> 16);
}
__device__ __forceinline__ float bf2f(ushort_t h) {
    return __uint_as_float((uint_t)h << 16);
}

__device__ __forceinline__ void gload16(const ushort_t* g, ushort_t* l) {
    __builtin_amdgcn_global_load_lds(
        (const __attribute__((address_space(1))) void*)g,
        (__attribute__((address_space(3))) void*)l,
        16, 0, 0);
}

// ===== Tile image (16 rows x 32 k = 512 elems = 1 KB) =====
// idx = slot*8 + (k&7), slot = ((k>>3)&3)*16 + (row&15)  [slot = quad*16+ln]
// A-frag & B-frag both read at lane*8 within a tile image.

// ---------- convert: x, w1, w2 -> hi-only tiled bf16 ----------
__global__ __launch_bounds__(256) void convertX(
    const float* __restrict__ x,  ushort_t* __restrict__ xh,
    const float* __restrict__ w1, ushort_t* __restrict__ w1h,
    const float* __restrict__ w2, ushort_t* __restrict__ w2h) {
    int sg = blockIdx.x * 256 + threadIdx.x;
    const float* src; ushort_t* dh;
    if (sg < 524288)      { src = x;  dh = xh; }
    else if (sg < 622592) { src = w1; dh = w1h; sg -= 524288; }
    else                  { src = w2; dh = w2h; sg -= 622592; }
    const int tile = sg >> 6, slot = sg & 63;
    const int row = (tile >> 4) * 16 + (slot & 15);
    const int k   = (tile & 15) * 32 + (slot >> 4) * 8;
    const float4 v0 = *(const float4*)&src[(size_t)row * 512 + k];
    const float4 v1 = *(const float4*)&src[(size_t)row * 512 + k + 4];
    const float vv[8] = {v0.x, v0.y, v0.z, v0.w, v1.x, v1.y, v1.z, v1.w};
    union { ushort_t u[8]; ushort4 v[2]; } h;
    #pragma unroll
    for (int j = 0; j < 8; j++) h.u[j] = f2bf(vv[j]);
    ((ushort4*)(dh + (size_t)sg * 8))[0] = h.v[0];
    ((ushort4*)(dh + (size_t)sg * 8))[1] = h.v[1];
}

// ---------- GEMM1: qkv projection, 1-term (hi x hi), BK=32, 2-deep dbuf ----
// 128x128 tile, grid (64, 12). by<4: q, [4,8): k, >=8: v.
__global__ __launch_bounds__(256) void gemm_qkv(
    const ushort_t* __restrict__ Ah,
    const ushort_t* __restrict__ Wh,
    const float* __restrict__ bias,
    ushort_t* __restrict__ qTh, ushort_t* __restrict__ qTl,
    ushort_t* __restrict__ kTh, ushort_t* __restrict__ kTl,
    ushort_t* __restrict__ vTh) {
    __shared__ __align__(16) ushort_t sAh[2][8 * 512];
    __shared__ __align__(16) ushort_t sWh[2][8 * 512];

    const int tid = threadIdx.x, lane = tid & 63, w = tid >> 6;
    const int wm = w & 1, wn = w >> 1, ln = lane & 15, quad = lane >> 4;
    const int bx = blockIdx.x, by = blockIdx.y;
    const int lo8 = lane * 8;
    const int wu = __builtin_amdgcn_readfirstlane(w);

    f32x4 acc[4][4];
    const f32x4 zero = {0.f, 0.f, 0.f, 0.f};
    #pragma unroll
    for (int i = 0; i < 4; i++)
        #pragma unroll
        for (int j = 0; j < 4; j++) acc[i][j] = zero;

    // staging: 16 images per k-group (A 8, Wh 8), 4 per wave
    const ushort_t* pb[4];
    ushort_t* db0[4];
    ushort_t* db1[4];
    #pragma unroll
    for (int t = 0; t < 4; t++) {
        const int g = wu * 4 + t;
        if (g < 8) {
            pb[t] = Ah + ((size_t)(bx * 8 + g) * 16) * 512;
            db0[t] = &sAh[0][g * 512]; db1[t] = &sAh[1][g * 512];
        } else {
            const int u = g - 8;
            pb[t] = Wh + ((size_t)(by * 8 + u) * 16) * 512;
            db0[t] = &sWh[0][u * 512]; db1[t] = &sWh[1][u * 512];
        }
    }

    // prologue: stage k-group 0 into buf 0
    #pragma unroll
    for (int t = 0; t < 4; t++)
        gload16(pb[t] + lo8, db0[t]);

    for (int kt = 0; kt < 16; kt++) {
        __syncthreads();
        if (kt < 15) {
            const int koff = (kt + 1) * 512;
            if ((kt + 1) & 1) {
                #pragma unroll
                for (int t = 0; t < 4; t++) gload16(pb[t] + koff + lo8, db1[t]);
            } else {
                #pragma unroll
                for (int t = 0; t < 4; t++) gload16(pb[t] + koff + lo8, db0[t]);
            }
        }
        const int cb = kt & 1;
        bf16x8 fah[4];
        #pragma unroll
        for (int i = 0; i < 4; i++)
            fah[i] = *(const bf16x8*)&sAh[cb][(wm * 4 + i) * 512 + lo8];
        #pragma unroll
        for (int j = 0; j < 4; j++) {
            const bf16x8 fbh = *(const bf16x8*)&sWh[cb][(wn * 4 + j) * 512 + lo8];
            #pragma unroll
            for (int i = 0; i < 4; i++)
                acc[i][j] = __builtin_amdgcn_mfma_f32_16x16x32_bf16(fah[i], fbh, acc[i][j], 0, 0, 0);
        }
    }

    // ---- epilogue: C/D layout col=ln (within j-tile), row=quad*4+r ----
    const int b = bx >> 5;
    const int h = 2 * (by & 3) + wn;
    if (by < 8) {
        ushort_t* dh = (by < 4) ? qTh : kTh;
        ushort_t* dl = (by < 4) ? qTl : kTl;
        #pragma unroll
        for (int i = 0; i < 4; i++) {
            const int rt = (bx & 31) * 8 + wm * 4 + i;
            const size_t tb = ((size_t)(b * 8 + h) * 256 + rt) * 2;
            #pragma unroll
            for (int j = 0; j < 4; j++) {
                const float bv = bias[by * 128 + wn * 64 + j * 16 + ln];
                const size_t tile = tb + (j >> 1);
                #pragma unroll
                for (int r = 0; r < 4; r++) {
                    const int slot = ((j * 2 + (ln >> 3)) & 3) * 16 + quad * 4 + r;
                    const size_t idx = tile * 512 + slot * 8 + (ln & 7);
                    const float v = acc[i][j][r] + bv;
                    const ushort_t hh = f2bf(v);
                    dh[idx] = hh;
                    dl[idx] = f2bf(v - bf2f(hh));
                }
            }
        }
    } else {
        const int kwin = (bx & 31) * 2 + wm;
        #pragma unroll
        for (int i = 0; i < 4; i++) {
            const int kk = i >> 1;
            #pragma unroll
            for (int j = 0; j < 4; j++) {
                const float bv = bias[by * 128 + wn * 64 + j * 16 + ln];
                const size_t tile = (((size_t)(b * 8 + h) * 64 + kwin) * 4 + j) * 2 + kk;
                #pragma unroll
                for (int r = 0; r < 4; r++) {
                    const int klq = quad * 4 + r;
                    const int slot = ((i & 1) * 2 + (klq >> 3)) * 16 + ln;
                    const size_t idx = tile * 512 + slot * 8 + (klq & 7);
                    vTh[idx] = f2bf(acc[i][j][r] + bv);
                }
            }
        }
    }
}

// ---------- attention: 128-query blocks, 8 waves (512 thr), 6 k-iters ----------
__global__ __launch_bounds__(512) void attn_mfma(
    const ushort_t* __restrict__ qTh, const ushort_t* __restrict__ qTl,
    const ushort_t* __restrict__ kTh, const ushort_t* __restrict__ kTl,
    const ushort_t* __restrict__ vTh,
    ushort_t* __restrict__ outh) {
    __shared__ __align__(16) ushort_t sKh[8 * 512];
    __shared__ __align__(16) ushort_t sKl[8 * 512];
    __shared__ __align__(16) ushort_t sV [8 * 512];
    __shared__ __align__(16) ushort_t sP [16 * 512];

    const int qs = blockIdx.x * 128;
    const int h = blockIdx.y, b = blockIdx.z;
    const int bh = b * 8 + h;
    const int tid = threadIdx.x, lane = tid & 63;
    const int w = tid >> 6, ln = lane & 15, quad = lane >> 4;
    const int lo8 = lane * 8;

    bf16x8 qf[2][2];
    {
        const size_t qt = ((size_t)bh * 256 + (qs >> 4) + w) * 2;
        qf[0][0] = *(const bf16x8*)(qTh + (qt + 0) * 512 + lo8);
        qf[1][0] = *(const bf16x8*)(qTh + (qt + 1) * 512 + lo8);
        qf[0][1] = *(const bf16x8*)(qTl + (qt + 0) * 512 + lo8);
        qf[1][1] = *(const bf16x8*)(qTl + (qt + 1) * 512 + lo8);
    }

    f32x4 oacc[4];
    const f32x4 zero = {0.f, 0.f, 0.f, 0.f};
    #pragma unroll
    for (int dt = 0; dt < 4; dt++) oacc[dt] = zero;
    float m_run[4], l_run[4];
    #pragma unroll
    for (int r = 0; r < 4; r++) { m_run[r] = -1e30f; l_run[r] = 0.f; }

    const float cscale = 0.125f * 1.44269504f;
    const int qlo = qs + 16 * w;

    for (int kt = 0; kt < 6; kt++) {
        const int ks = qs - 128 + kt * 64;

        __syncthreads();

        if (w < 4) {
            int st = (qs >> 4) - 8 + kt * 4 + w;
            st = st < 0 ? 0 : (st > 255 ? 255 : st);
            const size_t kb = ((size_t)bh * 256 + st) * 2 * 512 + lo8;
            gload16(kTh + kb,       &sKh[(w * 2 + 0) * 512]);
            gload16(kTh + kb + 512, &sKh[(w * 2 + 1) * 512]);
            gload16(kTl + kb,       &sKl[(w * 2 + 0) * 512]);
            gload16(kTl + kb + 512, &sKl[(w * 2 + 1) * 512]);
        } else {
            const int u = w - 4;
            int vw = (qs >> 6) - 2 + kt;
            vw = vw < 0 ? 0 : (vw > 63 ? 63 : vw);
            const size_t vb = (((size_t)bh * 64 + vw) * 4 + u) * 2 * 512 + lo8;
            gload16(vTh + vb,       &sV[(u * 2 + 0) * 512]);
            gload16(vTh + vb + 512, &sV[(u * 2 + 1) * 512]);
        }
        __syncthreads();

        f32x4 sacc[4];
        #pragma unroll
        for (int jt = 0; jt < 4; jt++) {
            f32x4 a = zero;
            const int klo = ks + 16 * jt;
            const bool dead = (klo > qlo + 15 + WIN) || (klo + 15 < qlo - WIN) ||
                              (klo >= L_SEQ) || (klo + 15 < 0);
            if (!dead) {
                #pragma unroll
                for (int kk = 0; kk < 2; kk++) {
                    const bf16x8 kh = *(const bf16x8*)&sKh[(jt * 2 + kk) * 512 + lo8];
                    const bf16x8 klo2 = *(const bf16x8*)&sKl[(jt * 2 + kk) * 512 + lo8];
                    a = __builtin_amdgcn_mfma_f32_16x16x32_bf16(qf[kk][0], kh, a, 0, 0, 0);
                    a = __builtin_amdgcn_mfma_f32_16x16x32_bf16(qf[kk][0], klo2, a, 0, 0, 0);
                    a = __builtin_amdgcn_mfma_f32_16x16x32_bf16(qf[kk][1], kh, a, 0, 0, 0);
                }
            }
            sacc[jt] = a;
        }

        float u[4][4];
        #pragma unroll
        for (int jt = 0; jt < 4; jt++) {
            const int kcol = ks + 16 * jt + ln;
            #pragma unroll
            for (int r = 0; r < 4; r++) {
                const int qrow = qlo + quad * 4 + r;
                const int dist = qrow > kcol ? qrow - kcol : kcol - qrow;
                const bool ok = (kcol >= 0) && (kcol < L_SEQ) && (dist >= 1) && (dist <= WIN);
                u[jt][r] = ok ? sacc[jt][r] * cscale : -INFINITY;
            }
        }
        float mk[4];
        #pragma unroll
        for (int r = 0; r < 4; r++)
            mk[r] = fmaxf(fmaxf(u[0][r], u[1][r]), fmaxf(u[2][r], u[3][r]));
        #pragma unroll
        for (int off = 1; off <= 8; off <<= 1)
            #pragma unroll
            for (int r = 0; r < 4; r++)
                mk[r] = fmaxf(mk[r], __shfl_xor(mk[r], off));

        float alpha[4], psum[4], p[4][4];
        #pragma unroll
        for (int r = 0; r < 4; r++) {
            const float mnew = fmaxf(fmaxf(m_run[r], mk[r]), -1e30f);
            alpha[r] = exp2f(m_run[r] - mnew);
            m_run[r] = mnew;
            psum[r] = 0.f;
            #pragma unroll
            for (int jt = 0; jt < 4; jt++) {
                p[jt][r] = exp2f(u[jt][r] - mnew);
                psum[r] += p[jt][r];
            }
        }
        #pragma unroll
        for (int off = 1; off <= 8; off <<= 1)
            #pragma unroll
            for (int r = 0; r < 4; r++)
                psum[r] += __shfl_xor(psum[r], off);
        #pragma unroll
        for (int r = 0; r < 4; r++)
            l_run[r] = l_run[r] * alpha[r] + psum[r];

        #pragma unroll
        for (int dt = 0; dt < 4; dt++)
            #pragma unroll
            for (int r = 0; r < 4; r++)
                oacc[dt][r] *= alpha[r];

        #pragma unroll
        for (int jt = 0; jt < 4; jt++)
            #pragma unroll
            for (int r = 0; r < 4; r++) {
                const int slot = ((jt & 1) * 2 + (ln >> 3)) * 16 + quad * 4 + r;
                sP[w * 1024 + (jt >> 1) * 512 + slot * 8 + (ln & 7)] = f2bf(p[jt][r]);
            }

        #pragma unroll
        for (int kk = 0; kk < 2; kk++) {
            const bf16x8 pf = *(const bf16x8*)&sP[w * 1024 + kk * 512 + lo8];
            #pragma unroll
            for (int dt = 0; dt < 4; dt++) {
                const bf16x8 vf = *(const bf16x8*)&sV[(dt * 2 + kk) * 512 + lo8];
                oacc[dt] = __builtin_amdgcn_mfma_f32_16x16x32_bf16(pf, vf, oacc[dt], 0, 0, 0);
            }
        }
    }

    const int Rt = ((b * L_SEQ + qs) >> 4) + w;
    #pragma unroll
    for (int r = 0; r < 4; r++) {
        const float inv_l = 1.f / l_run[r];
        #pragma unroll
        for (int dt = 0; dt < 4; dt++) {
            const float v = oacc[dt][r] * inv_l;
            const int tile = Rt * 16 + h * 2 + (dt >> 1);
            const int slot = ((dt & 1) * 2 + (ln >> 3)) * 16 + quad * 4 + r;
            const size_t idx = (size_t)tile * 512 + slot * 8 + (ln & 7);
            outh[idx] = f2bf(v);
        }
    }
}

// ---------- GEMM2: out projection, 128x64, 8 waves, BK=64, 1-term, dbuf -----
__global__ __launch_bounds__(512) void gemm_out(
    const ushort_t* __restrict__ Ah,
    const ushort_t* __restrict__ Wh,
    const float* __restrict__ bias, float* __restrict__ C) {
    __shared__ __align__(16) ushort_t sAh[2][16 * 512];
    __shared__ __align__(16) ushort_t sWh[2][8 * 512];

    const int tid = threadIdx.x, lane = tid & 63, w = tid >> 6;
    const int wm = w & 3, wn = w >> 2, ln = lane & 15, quad = lane >> 4;
    const int bx = blockIdx.x, by = blockIdx.y;
    const int lo8 = lane * 8;
    const int wu = __builtin_amdgcn_readfirstlane(w);

    f32x4 acc[2][2];
    const f32x4 zero = {0.f, 0.f, 0.f, 0.f};
    #pragma unroll
    for (int i = 0; i < 2; i++)
        #pragma unroll
        for (int j = 0; j < 2; j++) acc[i][j] = zero;

    // staging: 24 images per KT (A 16, Wh 8), 3 per wave
    const ushort_t* pb[3];
    ushort_t* db0[3];
    ushort_t* db1[3];
    #pragma unroll
    for (int t = 0; t < 3; t++) {
        const int g = wu * 3 + t;
        if (g < 16) {
            pb[t] = Ah + ((size_t)(bx * 8 + (g >> 1)) * 16 + (g & 1)) * 512;
            db0[t] = &sAh[0][g * 512]; db1[t] = &sAh[1][g * 512];
        } else {
            const int u = g - 16;
            pb[t] = Wh + ((size_t)(by * 4 + (u >> 1)) * 16 + (u & 1)) * 512;
            db0[t] = &sWh[0][u * 512]; db1[t] = &sWh[1][u * 512];
        }
    }

    // prologue
    #pragma unroll
    for (int t = 0; t < 3; t++)
        gload16(pb[t] + lo8, db0[t]);

    for (int KT = 0; KT < 8; KT++) {
        __syncthreads();
        if (KT < 7) {
            const int koff = (KT + 1) * 1024;
            if ((KT + 1) & 1) {
                #pragma unroll
                for (int t = 0; t < 3; t++) gload16(pb[t] + koff + lo8, db1[t]);
            } else {
                #pragma unroll
                for (int t = 0; t < 3; t++) gload16(pb[t] + koff + lo8, db0[t]);
            }
        }
        const int cb = KT & 1;
        #pragma unroll
        for (int ks = 0; ks < 2; ks++) {
            bf16x8 fah[2];
            #pragma unroll
            for (int i = 0; i < 2; i++)
                fah[i] = *(const bf16x8*)&sAh[cb][((wm * 2 + i) * 2 + ks) * 512 + lo8];
            #pragma unroll
            for (int j = 0; j < 2; j++) {
                const bf16x8 fbh = *(const bf16x8*)&sWh[cb][((wn * 2 + j) * 2 + ks) * 512 + lo8];
                #pragma unroll
                for (int i = 0; i < 2; i++)
                    acc[i][j] = __builtin_amdgcn_mfma_f32_16x16x32_bf16(fah[i], fbh, acc[i][j], 0, 0, 0);
            }
        }
    }

    #pragma unroll
    for (int i = 0; i < 2; i++) {
        const int row0 = bx * 128 + wm * 32 + i * 16 + quad * 4;
        #pragma unroll
        for (int j = 0; j < 2; j++) {
            const int col = by * 64 + wn * 32 + j * 16 + ln;
            const float bv = bias[col];
            #pragma unroll
            for (int r = 0; r < 4; r++)
                C[(size_t)(row0 + r) * E_DIM + col] = acc[i][j][r] + bv;
        }
    }
}

extern "C" void kernel_launch(void* const* d_in, const int* in_sizes, int n_in,
                              void* d_out, int out_size, void* d_ws, size_t ws_size,
                              hipStream_t stream) {
    const float* x         = (const float*)d_in[0];
    const float* in_proj_w = (const float*)d_in[1];
    const float* in_proj_b = (const float*)d_in[2];
    const float* out_w     = (const float*)d_in[3];
    const float* out_b     = (const float*)d_in[4];
    float* out = (float*)d_out;

    const int N = B_SZ * L_SEQ;  // 8192
    const size_t NE = (size_t)N * E_DIM;  // 4.19M elems

    char* p = (char*)d_ws;
    ushort_t* xh  = (ushort_t*)p; p += NE * 2;
    ushort_t* w1h = (ushort_t*)p; p += (size_t)3 * E_DIM * E_DIM * 2;
    ushort_t* w2h = (ushort_t*)p; p += (size_t)E_DIM * E_DIM * 2;
    ushort_t* qTh = (ushort_t*)p; p += NE * 2;
    ushort_t* qTl = (ushort_t*)p; p += NE * 2;
    ushort_t* kTh = (ushort_t*)p; p += NE * 2;
    ushort_t* kTl = (ushort_t*)p; p += NE * 2;
    ushort_t* vTh = (ushort_t*)p; p += NE * 2;
    ushort_t* ath = (ushort_t*)p; p += NE * 2;
    // total ~62 MB

    convertX<<<2560, 256, 0, stream>>>(x, xh, in_proj_w, w1h, out_w, w2h);

    gemm_qkv<<<dim3(64, 12), 256, 0, stream>>>(
        xh, w1h, in_proj_b, qTh, qTl, kTh, kTl, vTh);

    attn_mfma<<<dim3(L_SEQ / 128, H_DIM, B_SZ), 512, 0, stream>>>(
        qTh, qTl, kTh, kTl, vTh, ath);

    gemm_out<<<dim3(64, 8), 512, 0, stream>>>(
        ath, w2h, out_b, out);
}

// Round 15
// 135.372 us; speedup vs baseline: 1.4952x; 1.0660x over previous
//
#include <hip/hip_runtime.h>
#include <math.h>

#define E_DIM 512
#define H_DIM 8
#define WIN 128
#define L_SEQ 4096
#define B_SZ 2

typedef unsigned short ushort_t;
typedef unsigned int uint_t;
typedef __attribute__((ext_vector_type(8))) __bf16 bf16x8;
typedef __attribute__((ext_vector_type(4))) float f32x4;

// ---------- bf16 helpers (manual, RNE) ----------
__device__ __forceinline__ ushort_t f2bf(float f) {
    uint_t u = __float_as_uint(f);
    u = u + 0x7fffu + ((u >> 16) & 1u);
    return (ushort_t)(u >> 16);
}
__device__ __forceinline__ float bf2f(ushort_t h) {
    return __uint_as_float((uint_t)h << 16);
}

__device__ __forceinline__ void gload16(const ushort_t* g, ushort_t* l) {
    __builtin_amdgcn_global_load_lds(
        (const __attribute__((address_space(1))) void*)g,
        (__attribute__((address_space(3))) void*)l,
        16, 0, 0);
}

// ===== Tile image (16 rows x 32 k = 512 elems = 1 KB) =====
// idx = slot*8 + (k&7), slot = ((k>>3)&3)*16 + (row&15)  [slot = quad*16+ln]
// A-frag & B-frag both read at lane*8 within a tile image.

// ---------- convert: x, w1, w2 -> hi-only tiled bf16 ----------
__global__ __launch_bounds__(256) void convertX(
    const float* __restrict__ x,  ushort_t* __restrict__ xh,
    const float* __restrict__ w1, ushort_t* __restrict__ w1h,
    const float* __restrict__ w2, ushort_t* __restrict__ w2h) {
    int sg = blockIdx.x * 256 + threadIdx.x;
    const float* src; ushort_t* dh;
    if (sg < 524288)      { src = x;  dh = xh; }
    else if (sg < 622592) { src = w1; dh = w1h; sg -= 524288; }
    else                  { src = w2; dh = w2h; sg -= 622592; }
    const int tile = sg >> 6, slot = sg & 63;
    const int row = (tile >> 4) * 16 + (slot & 15);
    const int k   = (tile & 15) * 32 + (slot >> 4) * 8;
    const float4 v0 = *(const float4*)&src[(size_t)row * 512 + k];
    const float4 v1 = *(const float4*)&src[(size_t)row * 512 + k + 4];
    const float vv[8] = {v0.x, v0.y, v0.z, v0.w, v1.x, v1.y, v1.z, v1.w};
    union { ushort_t u[8]; ushort4 v[2]; } h;
    #pragma unroll
    for (int j = 0; j < 8; j++) h.u[j] = f2bf(vv[j]);
    ((ushort4*)(dh + (size_t)sg * 8))[0] = h.v[0];
    ((ushort4*)(dh + (size_t)sg * 8))[1] = h.v[1];
}

// ---------- GEMM1: qkv projection, 1-term (hi x hi), BK=32, 2-deep dbuf ----
// 128x128 tile, grid (64, 12). by<4: q, [4,8): k, >=8: v. All outputs hi-only.
__global__ __launch_bounds__(256) void gemm_qkv(
    const ushort_t* __restrict__ Ah,
    const ushort_t* __restrict__ Wh,
    const float* __restrict__ bias,
    ushort_t* __restrict__ qTh,
    ushort_t* __restrict__ kTh,
    ushort_t* __restrict__ vTh) {
    __shared__ __align__(16) ushort_t sAh[2][8 * 512];
    __shared__ __align__(16) ushort_t sWh[2][8 * 512];

    const int tid = threadIdx.x, lane = tid & 63, w = tid >> 6;
    const int wm = w & 1, wn = w >> 1, ln = lane & 15, quad = lane >> 4;
    const int bx = blockIdx.x, by = blockIdx.y;
    const int lo8 = lane * 8;
    const int wu = __builtin_amdgcn_readfirstlane(w);

    f32x4 acc[4][4];
    const f32x4 zero = {0.f, 0.f, 0.f, 0.f};
    #pragma unroll
    for (int i = 0; i < 4; i++)
        #pragma unroll
        for (int j = 0; j < 4; j++) acc[i][j] = zero;

    // staging: 16 images per k-group (A 8, Wh 8), 4 per wave
    const ushort_t* pb[4];
    ushort_t* db0[4];
    ushort_t* db1[4];
    #pragma unroll
    for (int t = 0; t < 4; t++) {
        const int g = wu * 4 + t;
        if (g < 8) {
            pb[t] = Ah + ((size_t)(bx * 8 + g) * 16) * 512;
            db0[t] = &sAh[0][g * 512]; db1[t] = &sAh[1][g * 512];
        } else {
            const int u = g - 8;
            pb[t] = Wh + ((size_t)(by * 8 + u) * 16) * 512;
            db0[t] = &sWh[0][u * 512]; db1[t] = &sWh[1][u * 512];
        }
    }

    // prologue: stage k-group 0 into buf 0
    #pragma unroll
    for (int t = 0; t < 4; t++)
        gload16(pb[t] + lo8, db0[t]);

    for (int kt = 0; kt < 16; kt++) {
        __syncthreads();
        if (kt < 15) {
            const int koff = (kt + 1) * 512;
            if ((kt + 1) & 1) {
                #pragma unroll
                for (int t = 0; t < 4; t++) gload16(pb[t] + koff + lo8, db1[t]);
            } else {
                #pragma unroll
                for (int t = 0; t < 4; t++) gload16(pb[t] + koff + lo8, db0[t]);
            }
        }
        const int cb = kt & 1;
        bf16x8 fah[4];
        #pragma unroll
        for (int i = 0; i < 4; i++)
            fah[i] = *(const bf16x8*)&sAh[cb][(wm * 4 + i) * 512 + lo8];
        #pragma unroll
        for (int j = 0; j < 4; j++) {
            const bf16x8 fbh = *(const bf16x8*)&sWh[cb][(wn * 4 + j) * 512 + lo8];
            #pragma unroll
            for (int i = 0; i < 4; i++)
                acc[i][j] = __builtin_amdgcn_mfma_f32_16x16x32_bf16(fah[i], fbh, acc[i][j], 0, 0, 0);
        }
    }

    // ---- epilogue: C/D layout col=ln (within j-tile), row=quad*4+r ----
    const int b = bx >> 5;
    const int h = 2 * (by & 3) + wn;
    if (by < 8) {
        ushort_t* dh = (by < 4) ? qTh : kTh;
        #pragma unroll
        for (int i = 0; i < 4; i++) {
            const int rt = (bx & 31) * 8 + wm * 4 + i;
            const size_t tb = ((size_t)(b * 8 + h) * 256 + rt) * 2;
            #pragma unroll
            for (int j = 0; j < 4; j++) {
                const float bv = bias[by * 128 + wn * 64 + j * 16 + ln];
                const size_t tile = tb + (j >> 1);
                #pragma unroll
                for (int r = 0; r < 4; r++) {
                    const int slot = ((j * 2 + (ln >> 3)) & 3) * 16 + quad * 4 + r;
                    const size_t idx = tile * 512 + slot * 8 + (ln & 7);
                    dh[idx] = f2bf(acc[i][j][r] + bv);
                }
            }
        }
    } else {
        const int kwin = (bx & 31) * 2 + wm;
        #pragma unroll
        for (int i = 0; i < 4; i++) {
            const int kk = i >> 1;
            #pragma unroll
            for (int j = 0; j < 4; j++) {
                const float bv = bias[by * 128 + wn * 64 + j * 16 + ln];
                const size_t tile = (((size_t)(b * 8 + h) * 64 + kwin) * 4 + j) * 2 + kk;
                #pragma unroll
                for (int r = 0; r < 4; r++) {
                    const int klq = quad * 4 + r;
                    const int slot = ((i & 1) * 2 + (klq >> 3)) * 16 + ln;
                    const size_t idx = tile * 512 + slot * 8 + (klq & 7);
                    vTh[idx] = f2bf(acc[i][j][r] + bv);
                }
            }
        }
    }
}

// ---------- attention: 128-q blocks, 8 waves, 1-term QK, K/V dbuf ----------
__global__ __launch_bounds__(512) void attn_mfma(
    const ushort_t* __restrict__ qTh,
    const ushort_t* __restrict__ kTh,
    const ushort_t* __restrict__ vTh,
    ushort_t* __restrict__ outh) {
    __shared__ __align__(16) ushort_t sKh[2][8 * 512];
    __shared__ __align__(16) ushort_t sV [2][8 * 512];
    __shared__ __align__(16) ushort_t sP [16 * 512];

    const int qs = blockIdx.x * 128;
    const int h = blockIdx.y, b = blockIdx.z;
    const int bh = b * 8 + h;
    const int tid = threadIdx.x, lane = tid & 63;
    const int w = tid >> 6, ln = lane & 15, quad = lane >> 4;
    const int lo8 = lane * 8;

    // Q fragments (hi only)
    bf16x8 qf[2];
    {
        const size_t qt = ((size_t)bh * 256 + (qs >> 4) + w) * 2;
        qf[0] = *(const bf16x8*)(qTh + (qt + 0) * 512 + lo8);
        qf[1] = *(const bf16x8*)(qTh + (qt + 1) * 512 + lo8);
    }

    f32x4 oacc[4];
    const f32x4 zero = {0.f, 0.f, 0.f, 0.f};
    #pragma unroll
    for (int dt = 0; dt < 4; dt++) oacc[dt] = zero;
    float m_run[4], l_run[4];
    #pragma unroll
    for (int r = 0; r < 4; r++) { m_run[r] = -1e30f; l_run[r] = 0.f; }

    const float cscale = 0.125f * 1.44269504f;
    const int qlo = qs + 16 * w;

    // staging lambda-free: wave w<4 stages K subtile jt=w (2 images);
    // w>=4 stages V subtile dt=w-4 (2 images).
    // prologue: kt = 0 into buf 0
    {
        if (w < 4) {
            int st = (qs >> 4) - 8 + w;
            st = st < 0 ? 0 : (st > 255 ? 255 : st);
            const size_t kb = ((size_t)bh * 256 + st) * 2 * 512 + lo8;
            gload16(kTh + kb,       &sKh[0][(w * 2 + 0) * 512]);
            gload16(kTh + kb + 512, &sKh[0][(w * 2 + 1) * 512]);
        } else {
            const int u = w - 4;
            int vw = (qs >> 6) - 2;
            vw = vw < 0 ? 0 : (vw > 63 ? 63 : vw);
            const size_t vb = (((size_t)bh * 64 + vw) * 4 + u) * 2 * 512 + lo8;
            gload16(vTh + vb,       &sV[0][(u * 2 + 0) * 512]);
            gload16(vTh + vb + 512, &sV[0][(u * 2 + 1) * 512]);
        }
    }

    for (int kt = 0; kt < 6; kt++) {
        const int ks = qs - 128 + kt * 64;

        __syncthreads();  // drains stage(kt); all waves done reading buf[(kt+1)&1]

        if (kt < 5) {
            const int nb = (kt + 1) & 1;
            if (w < 4) {
                int st = (qs >> 4) - 8 + (kt + 1) * 4 + w;
                st = st < 0 ? 0 : (st > 255 ? 255 : st);
                const size_t kb = ((size_t)bh * 256 + st) * 2 * 512 + lo8;
                gload16(kTh + kb,       &sKh[nb][(w * 2 + 0) * 512]);
                gload16(kTh + kb + 512, &sKh[nb][(w * 2 + 1) * 512]);
            } else {
                const int u = w - 4;
                int vw = (qs >> 6) - 2 + kt + 1;
                vw = vw < 0 ? 0 : (vw > 63 ? 63 : vw);
                const size_t vb = (((size_t)bh * 64 + vw) * 4 + u) * 2 * 512 + lo8;
                gload16(vTh + vb,       &sV[nb][(u * 2 + 0) * 512]);
                gload16(vTh + vb + 512, &sV[nb][(u * 2 + 1) * 512]);
            }
        }
        const int cb = kt & 1;

        // S = Q K^T (1-term hi x hi)
        f32x4 sacc[4];
        #pragma unroll
        for (int jt = 0; jt < 4; jt++) {
            f32x4 a = zero;
            const int klo = ks + 16 * jt;
            const bool dead = (klo > qlo + 15 + WIN) || (klo + 15 < qlo - WIN) ||
                              (klo >= L_SEQ) || (klo + 15 < 0);
            if (!dead) {
                #pragma unroll
                for (int kk = 0; kk < 2; kk++) {
                    const bf16x8 kh = *(const bf16x8*)&sKh[cb][(jt * 2 + kk) * 512 + lo8];
                    a = __builtin_amdgcn_mfma_f32_16x16x32_bf16(qf[kk], kh, a, 0, 0, 0);
                }
            }
            sacc[jt] = a;
        }

        // mask + online softmax
        float u[4][4];
        #pragma unroll
        for (int jt = 0; jt < 4; jt++) {
            const int kcol = ks + 16 * jt + ln;
            #pragma unroll
            for (int r = 0; r < 4; r++) {
                const int qrow = qlo + quad * 4 + r;
                const int dist = qrow > kcol ? qrow - kcol : kcol - qrow;
                const bool ok = (kcol >= 0) && (kcol < L_SEQ) && (dist >= 1) && (dist <= WIN);
                u[jt][r] = ok ? sacc[jt][r] * cscale : -INFINITY;
            }
        }
        float mk[4];
        #pragma unroll
        for (int r = 0; r < 4; r++)
            mk[r] = fmaxf(fmaxf(u[0][r], u[1][r]), fmaxf(u[2][r], u[3][r]));
        #pragma unroll
        for (int off = 1; off <= 8; off <<= 1)
            #pragma unroll
            for (int r = 0; r < 4; r++)
                mk[r] = fmaxf(mk[r], __shfl_xor(mk[r], off));

        float alpha[4], psum[4], p[4][4];
        #pragma unroll
        for (int r = 0; r < 4; r++) {
            const float mnew = fmaxf(fmaxf(m_run[r], mk[r]), -1e30f);
            alpha[r] = exp2f(m_run[r] - mnew);
            m_run[r] = mnew;
            psum[r] = 0.f;
            #pragma unroll
            for (int jt = 0; jt < 4; jt++) {
                p[jt][r] = exp2f(u[jt][r] - mnew);
                psum[r] += p[jt][r];
            }
        }
        #pragma unroll
        for (int off = 1; off <= 8; off <<= 1)
            #pragma unroll
            for (int r = 0; r < 4; r++)
                psum[r] += __shfl_xor(psum[r], off);
        #pragma unroll
        for (int r = 0; r < 4; r++)
            l_run[r] = l_run[r] * alpha[r] + psum[r];

        #pragma unroll
        for (int dt = 0; dt < 4; dt++)
            #pragma unroll
            for (int r = 0; r < 4; r++)
                oacc[dt][r] *= alpha[r];

        // P (hi only) -> own wave's A-frag tile images
        #pragma unroll
        for (int jt = 0; jt < 4; jt++)
            #pragma unroll
            for (int r = 0; r < 4; r++) {
                const int slot = ((jt & 1) * 2 + (ln >> 3)) * 16 + quad * 4 + r;
                sP[w * 1024 + (jt >> 1) * 512 + slot * 8 + (ln & 7)] = f2bf(p[jt][r]);
            }

        // O += P V (hi x hi)
        #pragma unroll
        for (int kk = 0; kk < 2; kk++) {
            const bf16x8 pf = *(const bf16x8*)&sP[w * 1024 + kk * 512 + lo8];
            #pragma unroll
            for (int dt = 0; dt < 4; dt++) {
                const bf16x8 vf = *(const bf16x8*)&sV[cb][(dt * 2 + kk) * 512 + lo8];
                oacc[dt] = __builtin_amdgcn_mfma_f32_16x16x32_bf16(pf, vf, oacc[dt], 0, 0, 0);
            }
        }
    }

    // epilogue: write hi bf16 in GEMM2's A-frag tiled layout
    const int Rt = ((b * L_SEQ + qs) >> 4) + w;
    #pragma unroll
    for (int r = 0; r < 4; r++) {
        const float inv_l = 1.f / l_run[r];
        #pragma unroll
        for (int dt = 0; dt < 4; dt++) {
            const float v = oacc[dt][r] * inv_l;
            const int tile = Rt * 16 + h * 2 + (dt >> 1);
            const int slot = ((dt & 1) * 2 + (ln >> 3)) * 16 + quad * 4 + r;
            const size_t idx = (size_t)tile * 512 + slot * 8 + (ln & 7);
            outh[idx] = f2bf(v);
        }
    }
}

// ---------- GEMM2: out projection, 128x64, 8 waves, BK=64, 1-term, dbuf -----
__global__ __launch_bounds__(512) void gemm_out(
    const ushort_t* __restrict__ Ah,
    const ushort_t* __restrict__ Wh,
    const float* __restrict__ bias, float* __restrict__ C) {
    __shared__ __align__(16) ushort_t sAh[2][16 * 512];
    __shared__ __align__(16) ushort_t sWh[2][8 * 512];

    const int tid = threadIdx.x, lane = tid & 63, w = tid >> 6;
    const int wm = w & 3, wn = w >> 2, ln = lane & 15, quad = lane >> 4;
    const int bx = blockIdx.x, by = blockIdx.y;
    const int lo8 = lane * 8;
    const int wu = __builtin_amdgcn_readfirstlane(w);

    f32x4 acc[2][2];
    const f32x4 zero = {0.f, 0.f, 0.f, 0.f};
    #pragma unroll
    for (int i = 0; i < 2; i++)
        #pragma unroll
        for (int j = 0; j < 2; j++) acc[i][j] = zero;

    // staging: 24 images per KT (A 16, Wh 8), 3 per wave
    const ushort_t* pb[3];
    ushort_t* db0[3];
    ushort_t* db1[3];
    #pragma unroll
    for (int t = 0; t < 3; t++) {
        const int g = wu * 3 + t;
        if (g < 16) {
            pb[t] = Ah + ((size_t)(bx * 8 + (g >> 1)) * 16 + (g & 1)) * 512;
            db0[t] = &sAh[0][g * 512]; db1[t] = &sAh[1][g * 512];
        } else {
            const int u = g - 16;
            pb[t] = Wh + ((size_t)(by * 4 + (u >> 1)) * 16 + (u & 1)) * 512;
            db0[t] = &sWh[0][u * 512]; db1[t] = &sWh[1][u * 512];
        }
    }

    // prologue
    #pragma unroll
    for (int t = 0; t < 3; t++)
        gload16(pb[t] + lo8, db0[t]);

    for (int KT = 0; KT < 8; KT++) {
        __syncthreads();
        if (KT < 7) {
            const int koff = (KT + 1) * 1024;
            if ((KT + 1) & 1) {
                #pragma unroll
                for (int t = 0; t < 3; t++) gload16(pb[t] + koff + lo8, db1[t]);
            } else {
                #pragma unroll
                for (int t = 0; t < 3; t++) gload16(pb[t] + koff + lo8, db0[t]);
            }
        }
        const int cb = KT & 1;
        #pragma unroll
        for (int ks = 0; ks < 2; ks++) {
            bf16x8 fah[2];
            #pragma unroll
            for (int i = 0; i < 2; i++)
                fah[i] = *(const bf16x8*)&sAh[cb][((wm * 2 + i) * 2 + ks) * 512 + lo8];
            #pragma unroll
            for (int j = 0; j < 2; j++) {
                const bf16x8 fbh = *(const bf16x8*)&sWh[cb][((wn * 2 + j) * 2 + ks) * 512 + lo8];
                #pragma unroll
                for (int i = 0; i < 2; i++)
                    acc[i][j] = __builtin_amdgcn_mfma_f32_16x16x32_bf16(fah[i], fbh, acc[i][j], 0, 0, 0);
            }
        }
    }

    #pragma unroll
    for (int i = 0; i < 2; i++) {
        const int row0 = bx * 128 + wm * 32 + i * 16 + quad * 4;
        #pragma unroll
        for (int j = 0; j < 2; j++) {
            const int col = by * 64 + wn * 32 + j * 16 + ln;
            const float bv = bias[col];
            #pragma unroll
            for (int r = 0; r < 4; r++)
                C[(size_t)(row0 + r) * E_DIM + col] = acc[i][j][r] + bv;
        }
    }
}

extern "C" void kernel_launch(void* const* d_in, const int* in_sizes, int n_in,
                              void* d_out, int out_size, void* d_ws, size_t ws_size,
                              hipStream_t stream) {
    const float* x         = (const float*)d_in[0];
    const float* in_proj_w = (const float*)d_in[1];
    const float* in_proj_b = (const float*)d_in[2];
    const float* out_w     = (const float*)d_in[3];
    const float* out_b     = (const float*)d_in[4];
    float* out = (float*)d_out;

    const int N = B_SZ * L_SEQ;  // 8192
    const size_t NE = (size_t)N * E_DIM;  // 4.19M elems

    char* p = (char*)d_ws;
    ushort_t* xh  = (ushort_t*)p; p += NE * 2;
    ushort_t* w1h = (ushort_t*)p; p += (size_t)3 * E_DIM * E_DIM * 2;
    ushort_t* w2h = (ushort_t*)p; p += (size_t)E_DIM * E_DIM * 2;
    ushort_t* qTh = (ushort_t*)p; p += NE * 2;
    ushort_t* kTh = (ushort_t*)p; p += NE * 2;
    ushort_t* vTh = (ushort_t*)p; p += NE * 2;
    ushort_t* ath = (ushort_t*)p; p += NE * 2;
    // total ~46 MB

    convertX<<<2560, 256, 0, stream>>>(x, xh, in_proj_w, w1h, out_w, w2h);

    gemm_qkv<<<dim3(64, 12), 256, 0, stream>>>(
        xh, w1h, in_proj_b, qTh, kTh, vTh);

    attn_mfma<<<dim3(L_SEQ / 128, H_DIM, B_SZ), 512, 0, stream>>>(
        qTh, kTh, vTh, ath);

    gemm_out<<<dim3(64, 8), 512, 0, stream>>>(
        ath, w2h, out_b, out);
}